// Round 1
// baseline (274.434 us; speedup 1.0000x reference)
//
#include <hip/hip_runtime.h>
#include <hip/hip_bf16.h>

// Problem constants (fixed by reference):
// B=2, C=256, H=W=64 -> N=4096, heads=4, D=64, 3D=192, M_embed = 4*192 = 768
#define B_   2
#define NH   4
#define D_   64
#define N_   4096
#define C_   256
#define ME   768

typedef float f32x4 __attribute__((ext_vector_type(4)));
typedef _Float16 f16x8 __attribute__((ext_vector_type(8)));
typedef _Float16 f16x4 __attribute__((ext_vector_type(4)));

// ---------------------------------------------------------------------------
// Kernel 1: qkv embed GEMM (fp32). C[b][m][n] = sum_k w_embed[m][k] * x[b][k][n] + b_embed[m]
// M=768, N=4096, K=256. 64x64 tile, BK=16, 256 thr, 4x4 micro-tile.
// ---------------------------------------------------------------------------
__global__ __launch_bounds__(256) void qkv_gemm(const float* __restrict__ x,
                                                const float* __restrict__ w,
                                                const float* __restrict__ bias,
                                                float* __restrict__ qkv) {
    __shared__ float As[16][68];   // [k][m], pad 4 (272B row = 16B aligned)
    __shared__ float Bs[16][68];   // [k][n]
    const int n0 = blockIdx.x * 64;
    const int m0 = blockIdx.y * 64;
    const int b  = blockIdx.z;
    const float* Bp = x + (size_t)b * C_ * N_;
    float* Cp = qkv + (size_t)b * ME * N_;
    const int t  = threadIdx.x;
    const int tn = t & 15, tm = t >> 4;
    float acc[4][4] = {};

    for (int k0 = 0; k0 < C_; k0 += 16) {
        __syncthreads();
        {
            // A tile: 64 m x 16 k (row-major global, transpose into [k][m])
            int m = t >> 2, kk = (t & 3) * 4;
            f32x4 a = *(const f32x4*)(w + (size_t)(m0 + m) * C_ + k0 + kk);
            As[kk + 0][m] = a[0]; As[kk + 1][m] = a[1];
            As[kk + 2][m] = a[2]; As[kk + 3][m] = a[3];
            // B tile: 16 k x 64 n (direct)
            int kb = t >> 4, nn = (t & 15) * 4;
            *(f32x4*)&Bs[kb][nn] = *(const f32x4*)(Bp + (size_t)(k0 + kb) * N_ + n0 + nn);
        }
        __syncthreads();
        #pragma unroll
        for (int kk = 0; kk < 16; ++kk) {
            f32x4 av = *(const f32x4*)&As[kk][tm * 4];
            f32x4 bv = *(const f32x4*)&Bs[kk][tn * 4];
            #pragma unroll
            for (int r = 0; r < 4; ++r)
                #pragma unroll
                for (int c = 0; c < 4; ++c)
                    acc[r][c] += av[r] * bv[c];
        }
    }
    #pragma unroll
    for (int r = 0; r < 4; ++r) {
        int m = m0 + tm * 4 + r;
        float bb = bias[m];
        f32x4 o = { acc[r][0] + bb, acc[r][1] + bb, acc[r][2] + bb, acc[r][3] + bb };
        *(f32x4*)(Cp + (size_t)m * N_ + n0 + tn * 4) = o;
    }
}

// ---------------------------------------------------------------------------
// Kernel 2: transpose q,k [d][n] fp32 -> [n][d] f16 (per b,h). Once, so MFMA
// staging loads in the attention loop are contiguous 16B copies.
// grid(64 ntile, 8 = sel*4+h, 2 b)
// ---------------------------------------------------------------------------
__global__ __launch_bounds__(256) void transpose_qk(const float* __restrict__ qkv,
                                                    _Float16* __restrict__ qT,
                                                    _Float16* __restrict__ kT) {
    __shared__ float T[64][68];
    const int nt  = blockIdx.x;
    const int h   = blockIdx.y & 3;
    const int sel = blockIdx.y >> 2;   // 0 = q, 1 = k
    const int b   = blockIdx.z;
    const float* src = qkv + ((size_t)b * ME + h * 192 + sel * 64) * N_ + nt * 64;
    _Float16* dst = (sel ? kT : qT) + ((size_t)(b * NH + h) * N_ + (size_t)nt * 64) * D_;
    const int t = threadIdx.x;
    #pragma unroll
    for (int r = 0; r < 4; ++r) {
        int idx = r * 256 + t;
        int d = idx >> 4, nc = (idx & 15) * 4;
        *(f32x4*)&T[d][nc] = *(const f32x4*)(src + (size_t)d * N_ + nc);
    }
    __syncthreads();
    #pragma unroll
    for (int r = 0; r < 2; ++r) {
        int idx = r * 256 + t;
        int n = idx >> 3, dg = (idx & 7) * 8;
        f16x8 v;
        #pragma unroll
        for (int c = 0; c < 8; ++c) v[c] = (_Float16)T[dg + c][n];
        *(f16x8*)(dst + (size_t)n * D_ + dg) = v;
    }
}

// ---------------------------------------------------------------------------
// Kernel 3: V fp32 [d][n] -> f16 [d][n] (layout already right for PV B-frags)
// ---------------------------------------------------------------------------
__global__ __launch_bounds__(256) void convert_v(const float* __restrict__ qkv,
                                                 _Float16* __restrict__ vB) {
    int gid = blockIdx.x * 256 + threadIdx.x;      // 2048 blocks * 256 * 4el = 2M el
    int row = gid >> 10, col = (gid & 1023) * 4;   // 1024 float4 per 4096-row
    int b = row >> 8, hd = row & 255, h = hd >> 6, d = hd & 63;
    const float* src = qkv + ((size_t)b * ME + h * 192 + 128 + d) * N_ + col;
    f32x4 v = *(const f32x4*)src;
    f16x4 o = { (_Float16)v[0], (_Float16)v[1], (_Float16)v[2], (_Float16)v[3] };
    *(f16x4*)(vB + (size_t)row * N_ + col) = o;
}

// ---------------------------------------------------------------------------
// Kernel 4: flash attention core, f16 MFMA 16x16x32, fp32 softmax/accum.
// 1 block = 64 queries of one (b,h); 4 waves, wave w owns rows w*16..w*16+15.
// Loop 64 key-tiles of 64. Layouts (verified mappings):
//   A-frag:  A[m=lane&15][k=quad*8+j],  B-frag: B[k=quad*8+j][n=lane&15]
//   C/D:     col=lane&15, row=quad*4+reg
// grid(64 qtile, 4 h, 2 b)
// ---------------------------------------------------------------------------
__global__ __launch_bounds__(256) void attn_kernel(const _Float16* __restrict__ qT,
                                                   const _Float16* __restrict__ kT,
                                                   const _Float16* __restrict__ vB,
                                                   float* __restrict__ y) {
    __shared__ __align__(16) union SM {
        struct { _Float16 Q[64][72], K[64][72], V[64][72], P[64][72]; } s;
        float Os[64][68];   // overlaps Q+K, used only in epilogue
    } sm;

    const int t = threadIdx.x;
    const int qt = blockIdx.x, h = blockIdx.y, b = blockIdx.z;
    const size_t bh = (size_t)(b * NH + h);
    const _Float16* qp = qT + (bh * N_ + (size_t)qt * 64) * D_;  // [i][d]
    const _Float16* kp = kT + bh * N_ * D_;                      // [j][d]
    const _Float16* vp = vB + bh * (size_t)D_ * N_;              // [d][n]
    const int lane = t & 63, w = t >> 6;
    const int quad = lane >> 4, l16 = lane & 15;

    // stage Q once: 64x64 f16 = 512 16B copies
    #pragma unroll
    for (int r = 0; r < 2; ++r) {
        int idx = r * 256 + t;
        int i = idx >> 3, dg = (idx & 7) * 8;
        *(f16x8*)&sm.s.Q[i][dg] = *(const f16x8*)(qp + (size_t)i * D_ + dg);
    }

    f32x4 oacc[4] = {};          // [dblk][reg]: rows quad*4+reg, col dblk*16+l16
    float m_run[4], l_run[4];
    #pragma unroll
    for (int r = 0; r < 4; ++r) { m_run[r] = -1e30f; l_run[r] = 0.f; }

    for (int jt = 0; jt < 64; ++jt) {
        __syncthreads();   // previous tile fully consumed (also makes Q visible, jt=0)
        #pragma unroll
        for (int r = 0; r < 2; ++r) {
            int idx = r * 256 + t;
            int row = idx >> 3, g = (idx & 7) * 8;
            *(f16x8*)&sm.s.K[row][g] = *(const f16x8*)(kp + ((size_t)(jt * 64 + row)) * D_ + g);
            *(f16x8*)&sm.s.V[row][g] = *(const f16x8*)(vp + (size_t)row * N_ + jt * 64 + g);
        }
        __syncthreads();

        // S = Q^T K (this wave's 16 rows x 64 cols)
        f32x4 sacc[4] = {};
        #pragma unroll
        for (int kc = 0; kc < 2; ++kc) {
            f16x8 aq = *(const f16x8*)&sm.s.Q[w * 16 + l16][kc * 32 + quad * 8];
            #pragma unroll
            for (int jb = 0; jb < 4; ++jb) {
                f16x8 bk = *(const f16x8*)&sm.s.K[jb * 16 + l16][kc * 32 + quad * 8];
                sacc[jb] = __builtin_amdgcn_mfma_f32_16x16x32_f16(aq, bk, sacc[jb], 0, 0, 0);
            }
        }

        // online softmax over this tile (row r owned by 16 lanes: same quad, l16 varies)
        float mnew[4], alpha[4], rsum[4];
        #pragma unroll
        for (int rg = 0; rg < 4; ++rg) {
            float mx = fmaxf(fmaxf(sacc[0][rg], sacc[1][rg]), fmaxf(sacc[2][rg], sacc[3][rg]));
            mx *= 0.125f;   // scale = D^-0.5
            mx = fmaxf(mx, __shfl_xor(mx, 1));
            mx = fmaxf(mx, __shfl_xor(mx, 2));
            mx = fmaxf(mx, __shfl_xor(mx, 4));
            mx = fmaxf(mx, __shfl_xor(mx, 8));
            mnew[rg]  = fmaxf(m_run[rg], mx);
            alpha[rg] = __expf(m_run[rg] - mnew[rg]);
            m_run[rg] = mnew[rg];
            rsum[rg]  = 0.f;
        }
        float p[4][4];
        #pragma unroll
        for (int jb = 0; jb < 4; ++jb)
            #pragma unroll
            for (int rg = 0; rg < 4; ++rg) {
                float pv = __expf(sacc[jb][rg] * 0.125f - mnew[rg]);
                p[jb][rg] = pv;
                rsum[rg] += pv;
            }
        #pragma unroll
        for (int rg = 0; rg < 4; ++rg) {
            float s = rsum[rg];
            s += __shfl_xor(s, 1); s += __shfl_xor(s, 2);
            s += __shfl_xor(s, 4); s += __shfl_xor(s, 8);
            l_run[rg] = l_run[rg] * alpha[rg] + s;
            #pragma unroll
            for (int db = 0; db < 4; ++db) oacc[db][rg] *= alpha[rg];
        }

        // P: C-layout -> A-layout round trip through LDS (same-wave rows only,
        // compiler inserts the lgkmcnt waits; no barrier needed)
        #pragma unroll
        for (int jb = 0; jb < 4; ++jb)
            #pragma unroll
            for (int rg = 0; rg < 4; ++rg)
                sm.s.P[w * 16 + quad * 4 + rg][jb * 16 + l16] = (_Float16)p[jb][rg];

        // O += P * V
        #pragma unroll
        for (int kc = 0; kc < 2; ++kc) {
            f16x8 ap = *(const f16x8*)&sm.s.P[w * 16 + l16][kc * 32 + quad * 8];
            #pragma unroll
            for (int db = 0; db < 4; ++db) {
                f16x8 bv = *(const f16x8*)&sm.s.V[db * 16 + l16][kc * 32 + quad * 8];
                oacc[db] = __builtin_amdgcn_mfma_f32_16x16x32_f16(ap, bv, oacc[db], 0, 0, 0);
            }
        }
    }

    // epilogue: normalize, transpose O[i][d] -> y[d][i] via LDS, write fp32
    float inv[4];
    #pragma unroll
    for (int rg = 0; rg < 4; ++rg) inv[rg] = 1.f / l_run[rg];
    __syncthreads();
    #pragma unroll
    for (int db = 0; db < 4; ++db)
        #pragma unroll
        for (int rg = 0; rg < 4; ++rg)
            sm.Os[db * 16 + l16][w * 16 + quad * 4 + rg] = oacc[db][rg] * inv[rg];
    __syncthreads();
    float* yp = y + ((size_t)(b * C_) + h * 64) * N_ + (size_t)qt * 64;
    #pragma unroll
    for (int r = 0; r < 4; ++r) {
        int idx = r * 256 + t;
        int d = idx >> 4, ic = (idx & 15) * 4;
        *(f32x4*)(yp + (size_t)d * N_ + ic) = *(const f32x4*)&sm.Os[d][ic];
    }
}

// ---------------------------------------------------------------------------
// Kernel 5: output projection + bias + residual (fp32).
// out[b][c][n] = sum_k w_out[k][c] * y[b][k][n] + b_out[c] + x[b][c][n]
// ---------------------------------------------------------------------------
__global__ __launch_bounds__(256) void proj_gemm(const float* __restrict__ y,
                                                 const float* __restrict__ w_out,
                                                 const float* __restrict__ b_out,
                                                 const float* __restrict__ x,
                                                 float* __restrict__ out) {
    __shared__ float As[16][68];   // [k][c]
    __shared__ float Bs[16][68];   // [k][n]
    const int n0 = blockIdx.x * 64;
    const int m0 = blockIdx.y * 64;   // c
    const int b  = blockIdx.z;
    const float* Bp = y + (size_t)b * C_ * N_;
    const int t  = threadIdx.x;
    const int tn = t & 15, tm = t >> 4;
    float acc[4][4] = {};

    for (int k0 = 0; k0 < C_; k0 += 16) {
        __syncthreads();
        {
            // A tile: w_out[k][c], already [k][m] orientation; coalesced over c
            int cc = t & 63, kk = t >> 6;
            #pragma unroll
            for (int r = 0; r < 4; ++r)
                As[kk + r * 4][cc] = w_out[(size_t)(k0 + kk + r * 4) * C_ + m0 + cc];
            int kb = t >> 4, nn = (t & 15) * 4;
            *(f32x4*)&Bs[kb][nn] = *(const f32x4*)(Bp + (size_t)(k0 + kb) * N_ + n0 + nn);
        }
        __syncthreads();
        #pragma unroll
        for (int kk = 0; kk < 16; ++kk) {
            f32x4 av = *(const f32x4*)&As[kk][tm * 4];
            f32x4 bv = *(const f32x4*)&Bs[kk][tn * 4];
            #pragma unroll
            for (int r = 0; r < 4; ++r)
                #pragma unroll
                for (int c = 0; c < 4; ++c)
                    acc[r][c] += av[r] * bv[c];
        }
    }
    const float* xr = x + (size_t)b * C_ * N_;
    float* op = out + (size_t)b * C_ * N_;
    #pragma unroll
    for (int r = 0; r < 4; ++r) {
        int m = m0 + tm * 4 + r;
        float bb = b_out[m];
        f32x4 xv = *(const f32x4*)(xr + (size_t)m * N_ + n0 + tn * 4);
        f32x4 o = { acc[r][0] + bb + xv[0], acc[r][1] + bb + xv[1],
                    acc[r][2] + bb + xv[2], acc[r][3] + bb + xv[3] };
        *(f32x4*)(op + (size_t)m * N_ + n0 + tn * 4) = o;
    }
}

// ---------------------------------------------------------------------------
// Workspace map (bytes; needs ~37.8 MB):
//   [0,            25165824)  qkv fp32 [B][768][4096]   (y fp32 aliases first 8.4MB,
//                                                        qkv fp32 is dead by then)
//   [25165824,     29360128)  qT  f16  [B][H][N][D]
//   [29360128,     33554432)  kT  f16  [B][H][N][D]
//   [33554432,     37748736)  vB  f16  [B][H][D][N]
// ---------------------------------------------------------------------------
extern "C" void kernel_launch(void* const* d_in, const int* in_sizes, int n_in,
                              void* d_out, int out_size, void* d_ws, size_t ws_size,
                              hipStream_t stream) {
    const float* x       = (const float*)d_in[0];
    const float* w_embed = (const float*)d_in[1];
    const float* b_embed = (const float*)d_in[2];
    const float* w_out   = (const float*)d_in[3];
    const float* b_out   = (const float*)d_in[4];
    float* out = (float*)d_out;

    float*    qkv = (float*)d_ws;                       // 6,291,456 fp32
    float*    y   = qkv;                                // aliases dead qkv region (2,097,152 fp32)
    _Float16* qT  = (_Float16*)(qkv + 6291456);         // 2,097,152 f16
    _Float16* kT  = qT + 2097152;
    _Float16* vB  = kT + 2097152;

    qkv_gemm   <<<dim3(64, 12, 2), 256, 0, stream>>>(x, w_embed, b_embed, qkv);
    transpose_qk<<<dim3(64,  8, 2), 256, 0, stream>>>(qkv, qT, kT);
    convert_v  <<<dim3(2048, 1, 1), 256, 0, stream>>>(qkv, vB);
    attn_kernel<<<dim3(64,  4, 2), 256, 0, stream>>>(qT, kT, vB, y);
    proj_gemm  <<<dim3(64,  4, 2), 256, 0, stream>>>(y, w_out, b_out, x, out);
}

// Round 2
// 169.452 us; speedup vs baseline: 1.6195x; 1.6195x over previous
//
#include <hip/hip_runtime.h>
#include <hip/hip_bf16.h>

// B=2, C=256, N=4096, heads=4, D=64, 3D=192, M_embed=768
#define NH   4
#define D_   64
#define N_   4096
#define C_   256
#define ME   768

typedef float    f32x4 __attribute__((ext_vector_type(4)));
typedef _Float16 f16x8 __attribute__((ext_vector_type(8)));
typedef _Float16 f16x4 __attribute__((ext_vector_type(4)));

// ---------------------------------------------------------------------------
// Prep 1: x fp32 [b][c][n] -> xT f16 [b][n][c]
// ---------------------------------------------------------------------------
__global__ __launch_bounds__(256) void xt_prep(const float* __restrict__ x,
                                               _Float16* __restrict__ xT) {
    __shared__ float T[64][68];
    const int n0 = blockIdx.x * 64, c0 = blockIdx.y * 64, b = blockIdx.z;
    const int t = threadIdx.x;
    const float* xp = x + ((size_t)b * C_ + c0) * N_ + n0;
    #pragma unroll
    for (int r = 0; r < 4; ++r) {
        int idx = r * 256 + t;
        int c = idx >> 4, ng = (idx & 15) * 4;
        *(f32x4*)&T[c][ng] = *(const f32x4*)(xp + (size_t)c * N_ + ng);
    }
    __syncthreads();
    _Float16* dp = xT + ((size_t)b * N_ + n0) * C_ + c0;
    #pragma unroll
    for (int r = 0; r < 2; ++r) {
        int idx = r * 256 + t;
        int n = idx >> 3, cg = (idx & 7) * 8;
        f16x8 v;
        #pragma unroll
        for (int j = 0; j < 8; ++j) v[j] = (_Float16)T[cg + j][n];
        *(f16x8*)(dp + (size_t)n * C_ + cg) = v;
    }
}

// ---------------------------------------------------------------------------
// Prep 2: w_embed fp32[768][256] -> wh f16 (same layout);
//         w_out fp32[256k][256c] -> w_outT f16 [c][k]
// blocks 0..95: wh copy; blocks 96..111: w_out transpose tiles
// ---------------------------------------------------------------------------
__global__ __launch_bounds__(256) void w_prep(const float* __restrict__ w_embed,
                                              const float* __restrict__ w_out,
                                              _Float16* __restrict__ wh,
                                              _Float16* __restrict__ w_outT) {
    __shared__ float T[64][68];
    const int t = threadIdx.x;
    if (blockIdx.x < 96) {
        int gid = blockIdx.x * 256 + t;   // each handles 8 elements
        const float* s = w_embed + (size_t)gid * 8;
        f32x4 a = *(const f32x4*)s, b2 = *(const f32x4*)(s + 4);
        f16x8 v = { (_Float16)a[0], (_Float16)a[1], (_Float16)a[2], (_Float16)a[3],
                    (_Float16)b2[0], (_Float16)b2[1], (_Float16)b2[2], (_Float16)b2[3] };
        *(f16x8*)(wh + (size_t)gid * 8) = v;
    } else {
        int tile = blockIdx.x - 96;
        int tc = tile & 3, tk = tile >> 2;
        #pragma unroll
        for (int r = 0; r < 4; ++r) {
            int idx = r * 256 + t;
            int kl = idx >> 4, cl = (idx & 15) * 4;
            *(f32x4*)&T[kl][cl] = *(const f32x4*)(w_out + (size_t)(tk * 64 + kl) * C_ + tc * 64 + cl);
        }
        __syncthreads();
        #pragma unroll
        for (int r = 0; r < 2; ++r) {
            int idx = r * 256 + t;
            int cl = idx >> 3, kg = (idx & 7) * 8;
            f16x8 v;
            #pragma unroll
            for (int j = 0; j < 8; ++j) v[j] = (_Float16)T[kg + j][cl];
            *(f16x8*)(w_outT + (size_t)(tc * 64 + cl) * C_ + tk * 64 + kg) = v;
        }
    }
}

// ---------------------------------------------------------------------------
// QKV GEMM (f16 MFMA 16x16x32): qkv[m][n] = sum_c wh[m][c] xT[n][c] + bias.
// 64x64 tile, BK=32, 256 thr (4 waves x 16 rows). Epilogue routes per m-tile:
//   mt%3==0 -> qT[bh][n][d], ==1 -> kT[bh][n][d], ==2 -> vB[bh][d][n]
// ---------------------------------------------------------------------------
__global__ __launch_bounds__(256) void qkv_gemm(const _Float16* __restrict__ xT,
                                                const _Float16* __restrict__ wh,
                                                const float* __restrict__ b_embed,
                                                _Float16* __restrict__ qT,
                                                _Float16* __restrict__ kT,
                                                _Float16* __restrict__ vB) {
    __shared__ __align__(16) union SM {
        struct { _Float16 A[64][40], X[64][40]; } s;
        float Os[64][68];
    } sm;
    const int n0 = blockIdx.x * 64, mt = blockIdx.y, b = blockIdx.z;
    const int m0 = mt * 64;
    const int t = threadIdx.x;
    const int lane = t & 63, w = t >> 6, quad = lane >> 4, l16 = lane & 15;
    const int srow = t >> 2, skoff = (t & 3) * 8;
    f32x4 acc[4] = {};
    for (int k0 = 0; k0 < C_; k0 += 32) {
        __syncthreads();
        *(f16x8*)&sm.s.A[srow][skoff] = *(const f16x8*)(wh + (size_t)(m0 + srow) * C_ + k0 + skoff);
        *(f16x8*)&sm.s.X[srow][skoff] = *(const f16x8*)(xT + ((size_t)b * N_ + n0 + srow) * C_ + k0 + skoff);
        __syncthreads();
        f16x8 af = *(const f16x8*)&sm.s.A[w * 16 + l16][quad * 8];
        #pragma unroll
        for (int nb = 0; nb < 4; ++nb) {
            f16x8 bf = *(const f16x8*)&sm.s.X[nb * 16 + l16][quad * 8];
            acc[nb] = __builtin_amdgcn_mfma_f32_16x16x32_f16(af, bf, acc[nb], 0, 0, 0);
        }
    }
    float bias[4];
    #pragma unroll
    for (int rg = 0; rg < 4; ++rg) bias[rg] = b_embed[m0 + w * 16 + quad * 4 + rg];
    __syncthreads();
    #pragma unroll
    for (int nb = 0; nb < 4; ++nb)
        #pragma unroll
        for (int rg = 0; rg < 4; ++rg)
            sm.Os[w * 16 + quad * 4 + rg][nb * 16 + l16] = acc[nb][rg] + bias[rg];
    __syncthreads();
    const int h = mt / 3, r3 = mt - h * 3;
    const int bh = b * NH + h;
    if (r3 < 2) {   // q or k: write [n][d]
        _Float16* dst = (r3 ? kT : qT) + ((size_t)bh * N_ + n0) * D_;
        #pragma unroll
        for (int r = 0; r < 2; ++r) {
            int idx = r * 256 + t;
            int n = idx >> 3, mg = (idx & 7) * 8;
            f16x8 v;
            #pragma unroll
            for (int j = 0; j < 8; ++j) v[j] = (_Float16)sm.Os[mg + j][n];
            *(f16x8*)(dst + (size_t)n * D_ + mg) = v;
        }
    } else {        // v: write [d][n]
        _Float16* dst = vB + (size_t)bh * D_ * N_ + n0;
        #pragma unroll
        for (int r = 0; r < 2; ++r) {
            int idx = r * 256 + t;
            int d = idx >> 3, ng = (idx & 7) * 8;
            f32x4 a = *(const f32x4*)&sm.Os[d][ng];
            f32x4 b2 = *(const f32x4*)&sm.Os[d][ng + 4];
            f16x8 v = { (_Float16)a[0], (_Float16)a[1], (_Float16)a[2], (_Float16)a[3],
                        (_Float16)b2[0], (_Float16)b2[1], (_Float16)b2[2], (_Float16)b2[3] };
            *(f16x8*)(dst + (size_t)d * N_ + ng) = v;
        }
    }
}

// ---------------------------------------------------------------------------
// Flash attention, St-scheme: St = K*Q^T (rows=j, cols=i). Q B-frags live in
// registers (loop-invariant). Lane owns column i = w*16+l16; 16 j per lane ->
// in-register softmax + 2 quad-shuffles. P transpose via 4 ds_write_b64.
// Split-KV x2 (blockIdx.z = b*2+s); partials (unnormalized O f16, m, l).
// grid(64 qtile, 4 h, 4 b*s)
// ---------------------------------------------------------------------------
__global__ __launch_bounds__(256) void attn_kernel(const _Float16* __restrict__ qT,
                                                   const _Float16* __restrict__ kT,
                                                   const _Float16* __restrict__ vB,
                                                   _Float16* __restrict__ opart,
                                                   float* __restrict__ mpart,
                                                   float* __restrict__ lpart) {
    __shared__ __align__(16) union SM {
        struct { _Float16 K[64][72], V[64][72], P[64][72]; } s;
        float Os[64][68];
    } sm;
    const int t = threadIdx.x;
    const int qt = blockIdx.x, h = blockIdx.y;
    const int b = blockIdx.z >> 1, s = blockIdx.z & 1;
    const int bh = b * NH + h, sbh = s * 8 + bh;
    const _Float16* kp = kT + (size_t)bh * N_ * D_;   // [j][d]
    const _Float16* vp = vB + (size_t)bh * D_ * N_;   // [d][n]
    const int lane = t & 63, w = t >> 6, quad = lane >> 4, l16 = lane & 15;

    // Q B-frags in registers: i = qt*64 + w*16 + l16
    const _Float16* qp = qT + ((size_t)bh * N_ + qt * 64 + w * 16 + l16) * D_;
    f16x8 qfrag0 = *(const f16x8*)(qp + quad * 8);
    f16x8 qfrag1 = *(const f16x8*)(qp + 32 + quad * 8);

    f32x4 oacc[4] = {};               // (i = w*16+quad*4+rg, d = db*16+l16)
    float m_run = -1e30f, l_run = 0.f;  // for column i = w*16+l16

    const int jt0 = s * 32;
    for (int jt = jt0; jt < jt0 + 32; ++jt) {
        __syncthreads();
        #pragma unroll
        for (int r = 0; r < 2; ++r) {
            int idx = r * 256 + t;
            int row = idx >> 3, g = (idx & 7) * 8;
            *(f16x8*)&sm.s.K[row][g] = *(const f16x8*)(kp + (size_t)(jt * 64 + row) * D_ + g);
            *(f16x8*)&sm.s.V[row][g] = *(const f16x8*)(vp + (size_t)row * N_ + jt * 64 + g);
        }
        __syncthreads();

        // St = K Q^T: rows j (4 jb blocks), cols i (this wave's 16)
        f32x4 sacc[4] = {};
        #pragma unroll
        for (int jb = 0; jb < 4; ++jb) {
            f16x8 kf0 = *(const f16x8*)&sm.s.K[jb * 16 + l16][quad * 8];
            sacc[jb] = __builtin_amdgcn_mfma_f32_16x16x32_f16(kf0, qfrag0, sacc[jb], 0, 0, 0);
            f16x8 kf1 = *(const f16x8*)&sm.s.K[jb * 16 + l16][32 + quad * 8];
            sacc[jb] = __builtin_amdgcn_mfma_f32_16x16x32_f16(kf1, qfrag1, sacc[jb], 0, 0, 0);
        }

        // online softmax: 16 j values in-register + 2 quad shuffles
        float mx = fmaxf(fmaxf(sacc[0][0], sacc[0][1]), fmaxf(sacc[0][2], sacc[0][3]));
        #pragma unroll
        for (int jb = 1; jb < 4; ++jb)
            mx = fmaxf(mx, fmaxf(fmaxf(sacc[jb][0], sacc[jb][1]), fmaxf(sacc[jb][2], sacc[jb][3])));
        mx *= 0.125f;
        mx = fmaxf(mx, __shfl_xor(mx, 16));
        mx = fmaxf(mx, __shfl_xor(mx, 32));
        float mnew  = fmaxf(m_run, mx);
        float alpha = __expf(m_run - mnew);
        float p[4][4];
        float rs = 0.f;
        #pragma unroll
        for (int jb = 0; jb < 4; ++jb)
            #pragma unroll
            for (int rg = 0; rg < 4; ++rg) {
                float pv = __expf(sacc[jb][rg] * 0.125f - mnew);
                p[jb][rg] = pv;
                rs += pv;
            }
        rs += __shfl_xor(rs, 16);
        rs += __shfl_xor(rs, 32);
        l_run = l_run * alpha + rs;
        m_run = mnew;

        // rescale O: alpha for row i-local = quad*4+rg lives at lane l16==that
        #pragma unroll
        for (int rg = 0; rg < 4; ++rg) {
            float a4 = __shfl(alpha, quad * 4 + rg);
            #pragma unroll
            for (int db = 0; db < 4; ++db) oacc[db][rg] *= a4;
        }

        // P store: 4 consecutive j per lane -> b64 writes (per-wave rows)
        #pragma unroll
        for (int jb = 0; jb < 4; ++jb) {
            f16x4 pv = { (_Float16)p[jb][0], (_Float16)p[jb][1],
                         (_Float16)p[jb][2], (_Float16)p[jb][3] };
            *(f16x4*)&sm.s.P[w * 16 + l16][jb * 16 + quad * 4] = pv;
        }

        // O += P * V
        #pragma unroll
        for (int kc = 0; kc < 2; ++kc) {
            f16x8 pf = *(const f16x8*)&sm.s.P[w * 16 + l16][kc * 32 + quad * 8];
            #pragma unroll
            for (int db = 0; db < 4; ++db) {
                f16x8 vf = *(const f16x8*)&sm.s.V[db * 16 + l16][kc * 32 + quad * 8];
                oacc[db] = __builtin_amdgcn_mfma_f32_16x16x32_f16(pf, vf, oacc[db], 0, 0, 0);
            }
        }
    }

    // epilogue: store m,l (quad 0 holds i = w*16+l16) and unnormalized O
    if (quad == 0) {
        mpart[(size_t)sbh * N_ + qt * 64 + w * 16 + l16] = m_run;
        lpart[(size_t)sbh * N_ + qt * 64 + w * 16 + l16] = l_run;
    }
    __syncthreads();
    #pragma unroll
    for (int db = 0; db < 4; ++db)
        #pragma unroll
        for (int rg = 0; rg < 4; ++rg)
            sm.Os[w * 16 + quad * 4 + rg][db * 16 + l16] = oacc[db][rg];
    __syncthreads();
    _Float16* op = opart + ((size_t)sbh * N_ + qt * 64) * D_;
    #pragma unroll
    for (int r = 0; r < 2; ++r) {
        int idx = r * 256 + t;
        int i = idx >> 3, dg = (idx & 7) * 8;
        f32x4 a = *(const f32x4*)&sm.Os[i][dg];
        f32x4 b2 = *(const f32x4*)&sm.Os[i][dg + 4];
        f16x8 v = { (_Float16)a[0], (_Float16)a[1], (_Float16)a[2], (_Float16)a[3],
                    (_Float16)b2[0], (_Float16)b2[1], (_Float16)b2[2], (_Float16)b2[3] };
        *(f16x8*)(op + (size_t)i * D_ + dg) = v;
    }
}

// ---------------------------------------------------------------------------
// Combine split-KV partials -> yT f16 [b][n][256] (n-major for proj B-frags)
// grid(128, 8 bh)
// ---------------------------------------------------------------------------
__global__ __launch_bounds__(256) void combine_kernel(const _Float16* __restrict__ opart,
                                                      const float* __restrict__ mpart,
                                                      const float* __restrict__ lpart,
                                                      _Float16* __restrict__ yT) {
    const int bhi = blockIdx.y;
    const int idx = blockIdx.x * 256 + threadIdx.x;
    const int n = idx >> 3, dg = (idx & 7) * 8;
    const int b = bhi >> 2, h = bhi & 3;
    float m0 = mpart[(size_t)bhi * N_ + n], m1 = mpart[(size_t)(8 + bhi) * N_ + n];
    float l0 = lpart[(size_t)bhi * N_ + n], l1 = lpart[(size_t)(8 + bhi) * N_ + n];
    float M  = fmaxf(m0, m1);
    float w0 = __expf(m0 - M), w1 = __expf(m1 - M);
    float inv = 1.f / (w0 * l0 + w1 * l1);
    w0 *= inv; w1 *= inv;
    f16x8 o0 = *(const f16x8*)(opart + ((size_t)bhi * N_ + n) * D_ + dg);
    f16x8 o1 = *(const f16x8*)(opart + ((size_t)(8 + bhi) * N_ + n) * D_ + dg);
    f16x8 v;
    #pragma unroll
    for (int j = 0; j < 8; ++j)
        v[j] = (_Float16)(w0 * (float)o0[j] + w1 * (float)o1[j]);
    *(f16x8*)(yT + ((size_t)b * N_ + n) * C_ + h * 64 + dg) = v;
}

// ---------------------------------------------------------------------------
// Output projection (f16 MFMA) + bias + residual:
// out[b][c][n] = sum_k yT[n][k] w_outT[c][k] + b_out[c] + x[b][c][n]
// ---------------------------------------------------------------------------
__global__ __launch_bounds__(256) void proj_gemm(const _Float16* __restrict__ yT,
                                                 const _Float16* __restrict__ w_outT,
                                                 const float* __restrict__ b_out,
                                                 const float* __restrict__ x,
                                                 float* __restrict__ out) {
    __shared__ __align__(16) union SM {
        struct { _Float16 A[64][40], Y[64][40]; } s;
        float Os[64][68];
    } sm;
    const int n0 = blockIdx.x * 64, c0 = blockIdx.y * 64, b = blockIdx.z;
    const int t = threadIdx.x;
    const int lane = t & 63, w = t >> 6, quad = lane >> 4, l16 = lane & 15;
    const int srow = t >> 2, skoff = (t & 3) * 8;
    f32x4 acc[4] = {};
    for (int k0 = 0; k0 < C_; k0 += 32) {
        __syncthreads();
        *(f16x8*)&sm.s.A[srow][skoff] = *(const f16x8*)(w_outT + (size_t)(c0 + srow) * C_ + k0 + skoff);
        *(f16x8*)&sm.s.Y[srow][skoff] = *(const f16x8*)(yT + ((size_t)b * N_ + n0 + srow) * C_ + k0 + skoff);
        __syncthreads();
        f16x8 af = *(const f16x8*)&sm.s.A[w * 16 + l16][quad * 8];
        #pragma unroll
        for (int nb = 0; nb < 4; ++nb) {
            f16x8 bf = *(const f16x8*)&sm.s.Y[nb * 16 + l16][quad * 8];
            acc[nb] = __builtin_amdgcn_mfma_f32_16x16x32_f16(af, bf, acc[nb], 0, 0, 0);
        }
    }
    float bias[4];
    #pragma unroll
    for (int rg = 0; rg < 4; ++rg) bias[rg] = b_out[c0 + w * 16 + quad * 4 + rg];
    __syncthreads();
    #pragma unroll
    for (int nb = 0; nb < 4; ++nb)
        #pragma unroll
        for (int rg = 0; rg < 4; ++rg)
            sm.Os[w * 16 + quad * 4 + rg][nb * 16 + l16] = acc[nb][rg] + bias[rg];
    __syncthreads();
    const float* xp = x + ((size_t)b * C_ + c0) * N_ + n0;
    float* op = out + ((size_t)b * C_ + c0) * N_ + n0;
    #pragma unroll
    for (int r = 0; r < 4; ++r) {
        int idx = r * 256 + t;
        int c = idx >> 4, ng = (idx & 15) * 4;
        f32x4 v  = *(const f32x4*)&sm.Os[c][ng];
        f32x4 xv = *(const f32x4*)(xp + (size_t)c * N_ + ng);
        f32x4 o  = { v[0] + xv[0], v[1] + xv[1], v[2] + xv[2], v[3] + xv[3] };
        *(f32x4*)(op + (size_t)c * N_ + ng) = o;
    }
}

// ---------------------------------------------------------------------------
// Workspace map (f16 element offsets from base; total ~30.4 MB):
//   xT      0         (2,097,152)   f16 [b][n][c]
//   wh      2,097,152 (196,608)     f16 [768][256]
//   w_outT  2,293,760 (65,536)      f16 [c][k]
//   qT      2,359,296 (2,097,152)   f16 [bh][n][d]
//   kT      4,456,448 (2,097,152)   f16 [bh][n][d]
//   vB      6,553,600 (2,097,152)   f16 [bh][d][n]
//   yT      8,650,752 (2,097,152)   f16 [b][n][256]
//   opart  10,747,904 (4,194,304)   f16 [s*8+bh][n][d]
//   mpart/lpart: f32 x 65,536 each after f16 region
// ---------------------------------------------------------------------------
extern "C" void kernel_launch(void* const* d_in, const int* in_sizes, int n_in,
                              void* d_out, int out_size, void* d_ws, size_t ws_size,
                              hipStream_t stream) {
    const float* x       = (const float*)d_in[0];
    const float* w_embed = (const float*)d_in[1];
    const float* b_embed = (const float*)d_in[2];
    const float* w_out   = (const float*)d_in[3];
    const float* b_out   = (const float*)d_in[4];
    float* out = (float*)d_out;

    _Float16* base   = (_Float16*)d_ws;
    _Float16* xT     = base;
    _Float16* wh     = base + 2097152;
    _Float16* w_outT = base + 2293760;
    _Float16* qT     = base + 2359296;
    _Float16* kT     = base + 4456448;
    _Float16* vB     = base + 6553600;
    _Float16* yT     = base + 8650752;
    _Float16* opart  = base + 10747904;
    float*    mpart  = (float*)(base + 14942208);
    float*    lpart  = mpart + 65536;

    xt_prep       <<<dim3(64, 4, 2),  256, 0, stream>>>(x, xT);
    w_prep        <<<dim3(112, 1, 1), 256, 0, stream>>>(w_embed, w_out, wh, w_outT);
    qkv_gemm      <<<dim3(64, 12, 2), 256, 0, stream>>>(xT, wh, b_embed, qT, kT, vB);
    attn_kernel   <<<dim3(64, 4, 4),  256, 0, stream>>>(qT, kT, vB, opart, mpart, lpart);
    combine_kernel<<<dim3(128, 8, 1), 256, 0, stream>>>(opart, mpart, lpart, yT);
    proj_gemm     <<<dim3(64, 4, 2),  256, 0, stream>>>(yT, w_outT, b_out, x, out);
}

// Round 4
// 169.092 us; speedup vs baseline: 1.6230x; 1.0021x over previous
//
#include <hip/hip_runtime.h>
#include <hip/hip_bf16.h>

// B=2, C=256, N=4096, heads=4, D=64, 3D=192, M_embed=768
#define NH   4
#define D_   64
#define N_   4096
#define C_   256
#define ME   768
#define SPLITS 3

typedef float    f32x4  __attribute__((ext_vector_type(4)));
typedef float    f32x16 __attribute__((ext_vector_type(16)));
typedef _Float16 f16x8  __attribute__((ext_vector_type(8)));
typedef _Float16 f16x4  __attribute__((ext_vector_type(4)));
typedef _Float16 f16x2  __attribute__((ext_vector_type(2)));

// ---------------------------------------------------------------------------
// Prep 1: x fp32 [b][c][n] -> xT f16 [b][n][c]
// ---------------------------------------------------------------------------
__global__ __launch_bounds__(256) void xt_prep(const float* __restrict__ x,
                                               _Float16* __restrict__ xT) {
    __shared__ float T[64][68];
    const int n0 = blockIdx.x * 64, c0 = blockIdx.y * 64, b = blockIdx.z;
    const int t = threadIdx.x;
    const float* xp = x + ((size_t)b * C_ + c0) * N_ + n0;
    #pragma unroll
    for (int r = 0; r < 4; ++r) {
        int idx = r * 256 + t;
        int c = idx >> 4, ng = (idx & 15) * 4;
        *(f32x4*)&T[c][ng] = *(const f32x4*)(xp + (size_t)c * N_ + ng);
    }
    __syncthreads();
    _Float16* dp = xT + ((size_t)b * N_ + n0) * C_ + c0;
    #pragma unroll
    for (int r = 0; r < 2; ++r) {
        int idx = r * 256 + t;
        int n = idx >> 3, cg = (idx & 7) * 8;
        f16x8 v;
        #pragma unroll
        for (int j = 0; j < 8; ++j) v[j] = (_Float16)T[cg + j][n];
        *(f16x8*)(dp + (size_t)n * C_ + cg) = v;
    }
}

// ---------------------------------------------------------------------------
// Prep 2: w_embed fp32[768][256] -> wh f16; w_out fp32[256k][256c] -> w_outT f16 [c][k]
// ---------------------------------------------------------------------------
__global__ __launch_bounds__(256) void w_prep(const float* __restrict__ w_embed,
                                              const float* __restrict__ w_out,
                                              _Float16* __restrict__ wh,
                                              _Float16* __restrict__ w_outT) {
    __shared__ float T[64][68];
    const int t = threadIdx.x;
    if (blockIdx.x < 96) {
        int gid = blockIdx.x * 256 + t;
        const float* s = w_embed + (size_t)gid * 8;
        f32x4 a = *(const f32x4*)s, b2 = *(const f32x4*)(s + 4);
        f16x8 v = { (_Float16)a[0], (_Float16)a[1], (_Float16)a[2], (_Float16)a[3],
                    (_Float16)b2[0], (_Float16)b2[1], (_Float16)b2[2], (_Float16)b2[3] };
        *(f16x8*)(wh + (size_t)gid * 8) = v;
    } else {
        int tile = blockIdx.x - 96;
        int tc = tile & 3, tk = tile >> 2;
        #pragma unroll
        for (int r = 0; r < 4; ++r) {
            int idx = r * 256 + t;
            int kl = idx >> 4, cl = (idx & 15) * 4;
            *(f32x4*)&T[kl][cl] = *(const f32x4*)(w_out + (size_t)(tk * 64 + kl) * C_ + tc * 64 + cl);
        }
        __syncthreads();
        #pragma unroll
        for (int r = 0; r < 2; ++r) {
            int idx = r * 256 + t;
            int cl = idx >> 3, kg = (idx & 7) * 8;
            f16x8 v;
            #pragma unroll
            for (int j = 0; j < 8; ++j) v[j] = (_Float16)T[kg + j][cl];
            *(f16x8*)(w_outT + (size_t)(tc * 64 + cl) * C_ + tk * 64 + kg) = v;
        }
    }
}

// ---------------------------------------------------------------------------
// QKV GEMM (f16 MFMA 16x16x32), epilogue routes to qT/kT [n][d] or vB [d][n]
// ---------------------------------------------------------------------------
__global__ __launch_bounds__(256) void qkv_gemm(const _Float16* __restrict__ xT,
                                                const _Float16* __restrict__ wh,
                                                const float* __restrict__ b_embed,
                                                _Float16* __restrict__ qT,
                                                _Float16* __restrict__ kT,
                                                _Float16* __restrict__ vB) {
    __shared__ __align__(16) union SM {
        struct { _Float16 A[64][40], X[64][40]; } s;
        float Os[64][68];
    } sm;
    const int n0 = blockIdx.x * 64, mt = blockIdx.y, b = blockIdx.z;
    const int m0 = mt * 64;
    const int t = threadIdx.x;
    const int lane = t & 63, w = t >> 6, quad = lane >> 4, l16 = lane & 15;
    const int srow = t >> 2, skoff = (t & 3) * 8;
    f32x4 acc[4] = {};
    for (int k0 = 0; k0 < C_; k0 += 32) {
        __syncthreads();
        *(f16x8*)&sm.s.A[srow][skoff] = *(const f16x8*)(wh + (size_t)(m0 + srow) * C_ + k0 + skoff);
        *(f16x8*)&sm.s.X[srow][skoff] = *(const f16x8*)(xT + ((size_t)b * N_ + n0 + srow) * C_ + k0 + skoff);
        __syncthreads();
        f16x8 af = *(const f16x8*)&sm.s.A[w * 16 + l16][quad * 8];
        #pragma unroll
        for (int nb = 0; nb < 4; ++nb) {
            f16x8 bf = *(const f16x8*)&sm.s.X[nb * 16 + l16][quad * 8];
            acc[nb] = __builtin_amdgcn_mfma_f32_16x16x32_f16(af, bf, acc[nb], 0, 0, 0);
        }
    }
    float bias[4];
    #pragma unroll
    for (int rg = 0; rg < 4; ++rg) bias[rg] = b_embed[m0 + w * 16 + quad * 4 + rg];
    __syncthreads();
    #pragma unroll
    for (int nb = 0; nb < 4; ++nb)
        #pragma unroll
        for (int rg = 0; rg < 4; ++rg)
            sm.Os[w * 16 + quad * 4 + rg][nb * 16 + l16] = acc[nb][rg] + bias[rg];
    __syncthreads();
    const int h = mt / 3, r3 = mt - h * 3;
    const int bh = b * NH + h;
    if (r3 < 2) {
        _Float16* dst = (r3 ? kT : qT) + ((size_t)bh * N_ + n0) * D_;
        #pragma unroll
        for (int r = 0; r < 2; ++r) {
            int idx = r * 256 + t;
            int n = idx >> 3, mg = (idx & 7) * 8;
            f16x8 v;
            #pragma unroll
            for (int j = 0; j < 8; ++j) v[j] = (_Float16)sm.Os[mg + j][n];
            *(f16x8*)(dst + (size_t)n * D_ + mg) = v;
        }
    } else {
        _Float16* dst = vB + (size_t)bh * D_ * N_ + n0;
        #pragma unroll
        for (int r = 0; r < 2; ++r) {
            int idx = r * 256 + t;
            int d = idx >> 3, ng = (idx & 7) * 8;
            f32x4 a = *(const f32x4*)&sm.Os[d][ng];
            f32x4 b2 = *(const f32x4*)&sm.Os[d][ng + 4];
            f16x8 v = { (_Float16)a[0], (_Float16)a[1], (_Float16)a[2], (_Float16)a[3],
                        (_Float16)b2[0], (_Float16)b2[1], (_Float16)b2[2], (_Float16)b2[3] };
            *(f16x8*)(dst + (size_t)d * N_ + ng) = v;
        }
    }
}

// ---------------------------------------------------------------------------
// Flash attention v3b: 32x32x16 MFMA, block = 128 i x 64 j, 4 waves x 32 i.
//   St = K*Q^T  (A = K-frag from LDS, B = Q-frag in registers, pre-scaled by
//                0.125*log2e -> softmax in exp2 domain)
//   Ot = Vt*P   (A = Vt-frag from LDS, B = P built in registers from St
//                C-layout via shfl_xor(32) half exchanges -> NO P LDS trip)
// 32x32x16 layouts: A[m=lane&31][k=(lane>>5)*8+j]; B[k=(lane>>5)*8+j][n=lane&31]
// C/D: col=lane&31, row=(reg&3)+8*(reg>>2)+4*(lane>>5)
// Staging: two-pass, 512 f16x8 writes = full 2x 64x64 tile (round-3 bug fix).
// LDS rows padded to 76 f16 (stride 38 dwords -> 2-way bank alias = free).
// Split-KV x3. grid(32 qtile, 4 h, 6 = b*3+s)
// ---------------------------------------------------------------------------
__global__ __launch_bounds__(256) void attn_kernel(const _Float16* __restrict__ qT,
                                                   const _Float16* __restrict__ kT,
                                                   const _Float16* __restrict__ vB,
                                                   _Float16* __restrict__ opart,
                                                   float* __restrict__ mpart,
                                                   float* __restrict__ lpart) {
    __shared__ __align__(16) union SM {
        struct { _Float16 K[64][76], V[64][76]; } s;   // 19456 B
        _Float16 Os[128][76];                           // 19456 B (epilogue)
    } sm;
    const int t = threadIdx.x;
    const int qt = blockIdx.x, h = blockIdx.y;
    const int b = blockIdx.z / SPLITS, s = blockIdx.z % SPLITS;
    const int bh = b * NH + h, sbh = s * 8 + bh;
    const _Float16* kp = kT + (size_t)bh * N_ * D_;   // [j][d]
    const _Float16* vp = vB + (size_t)bh * D_ * N_;   // [d][n]
    const int lane = t & 63, w = t >> 6, l32 = lane & 31, hl = lane >> 5;
    const bool hl1 = (hl != 0);
    const int srow = t >> 3, scol = (t & 7) * 8;       // two-pass: rows srow, srow+32

    // Q B-frags in registers, pre-scaled by 2^-3 * log2(e)
    const _Float16* qp = qT + ((size_t)bh * N_ + qt * 128 + w * 32 + l32) * D_;
    f16x8 qf[4];
    #pragma unroll
    for (int kc = 0; kc < 4; ++kc) {
        qf[kc] = *(const f16x8*)(qp + kc * 16 + hl * 8);
        qf[kc] *= (_Float16)0.18033688f;
    }

    f32x16 oacc0 = {}, oacc1 = {};   // d-blocks 0,1; col i = w*32+l32
    float m_run = -3.0e38f, l_run = 0.f;

    const int jt_lo = (s * 64) / SPLITS, jt_hi = ((s + 1) * 64) / SPLITS;
    f16x8 kpre[2], vpre[2];
    #pragma unroll
    for (int r = 0; r < 2; ++r) {
        int row = srow + r * 32;
        kpre[r] = *(const f16x8*)(kp + (size_t)(jt_lo * 64 + row) * D_ + scol);
        vpre[r] = *(const f16x8*)(vp + (size_t)row * N_ + jt_lo * 64 + scol);
    }

    for (int jt = jt_lo; jt < jt_hi; ++jt) {
        __syncthreads();
        #pragma unroll
        for (int r = 0; r < 2; ++r) {
            int row = srow + r * 32;
            *(f16x8*)&sm.s.K[row][scol] = kpre[r];
            *(f16x8*)&sm.s.V[row][scol] = vpre[r];
        }
        __syncthreads();
        if (jt + 1 < jt_hi) {
            #pragma unroll
            for (int r = 0; r < 2; ++r) {
                int row = srow + r * 32;
                kpre[r] = *(const f16x8*)(kp + (size_t)((jt + 1) * 64 + row) * D_ + scol);
                vpre[r] = *(const f16x8*)(vp + (size_t)row * N_ + (jt + 1) * 64 + scol);
            }
        }

        // ---- St = K Q^T : two 32x32 tiles (jb=0,1), k over d=64 (4 steps)
        f32x16 sa0 = {}, sa1 = {};
        #pragma unroll
        for (int kc = 0; kc < 4; ++kc) {
            f16x8 kf0 = *(const f16x8*)&sm.s.K[l32][kc * 16 + hl * 8];
            sa0 = __builtin_amdgcn_mfma_f32_32x32x16_f16(kf0, qf[kc], sa0, 0, 0, 0);
            f16x8 kf1 = *(const f16x8*)&sm.s.K[32 + l32][kc * 16 + hl * 8];
            sa1 = __builtin_amdgcn_mfma_f32_32x32x16_f16(kf1, qf[kc], sa1, 0, 0, 0);
        }

        // ---- online softmax (exp2 domain); column state shared with hl-partner
        float mx = fmaxf(sa0[0], sa0[1]);
        #pragma unroll
        for (int r = 2; r < 16; ++r) mx = fmaxf(mx, sa0[r]);
        #pragma unroll
        for (int r = 0; r < 16; ++r) mx = fmaxf(mx, sa1[r]);
        mx = fmaxf(mx, __shfl_xor(mx, 32));
        float mnew  = fmaxf(m_run, mx);
        float alpha = exp2f(m_run - mnew);
        float rs = 0.f;
        #pragma unroll
        for (int r = 0; r < 16; ++r) { sa0[r] = exp2f(sa0[r] - mnew); rs += sa0[r]; }
        #pragma unroll
        for (int r = 0; r < 16; ++r) { sa1[r] = exp2f(sa1[r] - mnew); rs += sa1[r]; }
        rs += __shfl_xor(rs, 32);
        l_run = l_run * alpha + rs;
        m_run = mnew;
        #pragma unroll
        for (int r = 0; r < 16; ++r) { oacc0[r] *= alpha; oacc1[r] *= alpha; }

        // ---- P -> B-frags in registers (per jb: pack pairs, exchange halves)
        #pragma unroll
        for (int jb = 0; jb < 2; ++jb) {
            const f32x16& sa = jb ? sa1 : sa0;
            int P[8], X[8];
            #pragma unroll
            for (int q = 0; q < 8; ++q) {
                f16x2 pk = { (_Float16)sa[2 * q], (_Float16)sa[2 * q + 1] };
                P[q] = __builtin_bit_cast(int, pk);
            }
            #pragma unroll
            for (int q = 0; q < 8; ++q) X[q] = __shfl_xor(P[q], 32);
            union FU { f16x8 v; int d[4]; } f0, f1;
            f0.d[0] = hl1 ? X[2] : P[0];
            f0.d[1] = hl1 ? X[3] : P[1];
            f0.d[2] = hl1 ? P[2] : X[0];
            f0.d[3] = hl1 ? P[3] : X[1];
            f1.d[0] = hl1 ? X[6] : P[4];
            f1.d[1] = hl1 ? X[7] : P[5];
            f1.d[2] = hl1 ? P[6] : X[4];
            f1.d[3] = hl1 ? P[7] : X[5];
            // ---- Ot += Vt * P for this jb (k-chunks jb*32 and jb*32+16)
            f16x8 vf = *(const f16x8*)&sm.s.V[l32][jb * 32 + hl * 8];
            oacc0 = __builtin_amdgcn_mfma_f32_32x32x16_f16(vf, f0.v, oacc0, 0, 0, 0);
            vf = *(const f16x8*)&sm.s.V[l32][jb * 32 + 16 + hl * 8];
            oacc0 = __builtin_amdgcn_mfma_f32_32x32x16_f16(vf, f1.v, oacc0, 0, 0, 0);
            vf = *(const f16x8*)&sm.s.V[32 + l32][jb * 32 + hl * 8];
            oacc1 = __builtin_amdgcn_mfma_f32_32x32x16_f16(vf, f0.v, oacc1, 0, 0, 0);
            vf = *(const f16x8*)&sm.s.V[32 + l32][jb * 32 + 16 + hl * 8];
            oacc1 = __builtin_amdgcn_mfma_f32_32x32x16_f16(vf, f1.v, oacc1, 0, 0, 0);
        }
    }

    // ---- epilogue: per-split normalized O -> Os[i][d] f16, plus m,l
    float linv = 1.f / l_run;
    if (hl == 0) {
        mpart[(size_t)sbh * N_ + qt * 128 + w * 32 + l32] = m_run;
        lpart[(size_t)sbh * N_ + qt * 128 + w * 32 + l32] = l_run;
    }
    __syncthreads();
    #pragma unroll
    for (int db = 0; db < 2; ++db) {
        const f32x16& oc = db ? oacc1 : oacc0;
        #pragma unroll
        for (int rq = 0; rq < 4; ++rq) {
            f16x4 pv = { (_Float16)(oc[rq * 4 + 0] * linv), (_Float16)(oc[rq * 4 + 1] * linv),
                         (_Float16)(oc[rq * 4 + 2] * linv), (_Float16)(oc[rq * 4 + 3] * linv) };
            *(f16x4*)&sm.Os[w * 32 + l32][db * 32 + rq * 8 + hl * 4] = pv;
        }
    }
    __syncthreads();
    _Float16* op = opart + ((size_t)sbh * N_ + qt * 128) * D_;
    #pragma unroll
    for (int r = 0; r < 4; ++r) {
        int idx = r * 256 + t;
        int i = idx >> 3, ch = (idx & 7) * 8;
        *(f16x8*)(op + (size_t)i * D_ + ch) = *(const f16x8*)&sm.Os[i][ch];
    }
}

// ---------------------------------------------------------------------------
// Combine 3 split-KV partials (each per-split normalized) -> yT f16 [b][n][256]
// ---------------------------------------------------------------------------
__global__ __launch_bounds__(256) void combine_kernel(const _Float16* __restrict__ opart,
                                                      const float* __restrict__ mpart,
                                                      const float* __restrict__ lpart,
                                                      _Float16* __restrict__ yT) {
    const int bhi = blockIdx.y;
    const int idx = blockIdx.x * 256 + threadIdx.x;
    const int n = idx >> 3, dg = (idx & 7) * 8;
    const int b = bhi >> 2, h = bhi & 3;
    float m0 = mpart[(size_t)bhi * N_ + n];
    float m1 = mpart[(size_t)(8 + bhi) * N_ + n];
    float m2 = mpart[(size_t)(16 + bhi) * N_ + n];
    float l0 = lpart[(size_t)bhi * N_ + n];
    float l1 = lpart[(size_t)(8 + bhi) * N_ + n];
    float l2 = lpart[(size_t)(16 + bhi) * N_ + n];
    float M  = fmaxf(m0, fmaxf(m1, m2));
    float w0 = exp2f(m0 - M) * l0, w1 = exp2f(m1 - M) * l1, w2 = exp2f(m2 - M) * l2;
    float inv = 1.f / (w0 + w1 + w2);
    w0 *= inv; w1 *= inv; w2 *= inv;
    f16x8 o0 = *(const f16x8*)(opart + ((size_t)bhi * N_ + n) * D_ + dg);
    f16x8 o1 = *(const f16x8*)(opart + ((size_t)(8 + bhi) * N_ + n) * D_ + dg);
    f16x8 o2 = *(const f16x8*)(opart + ((size_t)(16 + bhi) * N_ + n) * D_ + dg);
    f16x8 v;
    #pragma unroll
    for (int j = 0; j < 8; ++j)
        v[j] = (_Float16)(w0 * (float)o0[j] + w1 * (float)o1[j] + w2 * (float)o2[j]);
    *(f16x8*)(yT + ((size_t)b * N_ + n) * C_ + h * 64 + dg) = v;
}

// ---------------------------------------------------------------------------
// Output projection (f16 MFMA) + bias + residual
// ---------------------------------------------------------------------------
__global__ __launch_bounds__(256) void proj_gemm(const _Float16* __restrict__ yT,
                                                 const _Float16* __restrict__ w_outT,
                                                 const float* __restrict__ b_out,
                                                 const float* __restrict__ x,
                                                 float* __restrict__ out) {
    __shared__ __align__(16) union SM {
        struct { _Float16 A[64][40], Y[64][40]; } s;
        float Os[64][68];
    } sm;
    const int n0 = blockIdx.x * 64, c0 = blockIdx.y * 64, b = blockIdx.z;
    const int t = threadIdx.x;
    const int lane = t & 63, w = t >> 6, quad = lane >> 4, l16 = lane & 15;
    const int srow = t >> 2, skoff = (t & 3) * 8;
    f32x4 acc[4] = {};
    for (int k0 = 0; k0 < C_; k0 += 32) {
        __syncthreads();
        *(f16x8*)&sm.s.A[srow][skoff] = *(const f16x8*)(w_outT + (size_t)(c0 + srow) * C_ + k0 + skoff);
        *(f16x8*)&sm.s.Y[srow][skoff] = *(const f16x8*)(yT + ((size_t)b * N_ + n0 + srow) * C_ + k0 + skoff);
        __syncthreads();
        f16x8 af = *(const f16x8*)&sm.s.A[w * 16 + l16][quad * 8];
        #pragma unroll
        for (int nb = 0; nb < 4; ++nb) {
            f16x8 bf = *(const f16x8*)&sm.s.Y[nb * 16 + l16][quad * 8];
            acc[nb] = __builtin_amdgcn_mfma_f32_16x16x32_f16(af, bf, acc[nb], 0, 0, 0);
        }
    }
    float bias[4];
    #pragma unroll
    for (int rg = 0; rg < 4; ++rg) bias[rg] = b_out[c0 + w * 16 + quad * 4 + rg];
    __syncthreads();
    #pragma unroll
    for (int nb = 0; nb < 4; ++nb)
        #pragma unroll
        for (int rg = 0; rg < 4; ++rg)
            sm.Os[w * 16 + quad * 4 + rg][nb * 16 + l16] = acc[nb][rg] + bias[rg];
    __syncthreads();
    const float* xp = x + ((size_t)b * C_ + c0) * N_ + n0;
    float* op = out + ((size_t)b * C_ + c0) * N_ + n0;
    #pragma unroll
    for (int r = 0; r < 4; ++r) {
        int idx = r * 256 + t;
        int c = idx >> 4, ng = (idx & 15) * 4;
        f32x4 v  = *(const f32x4*)&sm.Os[c][ng];
        f32x4 xv = *(const f32x4*)(xp + (size_t)c * N_ + ng);
        f32x4 o  = { v[0] + xv[0], v[1] + xv[1], v[2] + xv[2], v[3] + xv[3] };
        *(f32x4*)(op + (size_t)c * N_ + ng) = o;
    }
}

// ---------------------------------------------------------------------------
// Workspace map (f16 element offsets; total ~34.9 MB):
//   xT 0 | wh 2,097,152 | w_outT 2,293,760 | qT 2,359,296 | kT 4,456,448
//   vB 6,553,600 | yT 8,650,752 | opart 10,747,904 (s*8+bh)[n][d]
//   mpart f32 @ base+17,039,360 (98,304) ; lpart follows
// ---------------------------------------------------------------------------
extern "C" void kernel_launch(void* const* d_in, const int* in_sizes, int n_in,
                              void* d_out, int out_size, void* d_ws, size_t ws_size,
                              hipStream_t stream) {
    const float* x       = (const float*)d_in[0];
    const float* w_embed = (const float*)d_in[1];
    const float* b_embed = (const float*)d_in[2];
    const float* w_out   = (const float*)d_in[3];
    const float* b_out   = (const float*)d_in[4];
    float* out = (float*)d_out;

    _Float16* base   = (_Float16*)d_ws;
    _Float16* xT     = base;
    _Float16* wh     = base + 2097152;
    _Float16* w_outT = base + 2293760;
    _Float16* qT     = base + 2359296;
    _Float16* kT     = base + 4456448;
    _Float16* vB     = base + 6553600;
    _Float16* yT     = base + 8650752;
    _Float16* opart  = base + 10747904;
    float*    mpart  = (float*)(base + 17039360);
    float*    lpart  = mpart + 98304;

    xt_prep       <<<dim3(64, 4, 2),  256, 0, stream>>>(x, xT);
    w_prep        <<<dim3(112, 1, 1), 256, 0, stream>>>(w_embed, w_out, wh, w_outT);
    qkv_gemm      <<<dim3(64, 12, 2), 256, 0, stream>>>(xT, wh, b_embed, qT, kT, vB);
    attn_kernel   <<<dim3(32, 4, 6),  256, 0, stream>>>(qT, kT, vB, opart, mpart, lpart);
    combine_kernel<<<dim3(128, 8, 1), 256, 0, stream>>>(opart, mpart, lpart, yT);
    proj_gemm     <<<dim3(64, 4, 2),  256, 0, stream>>>(yT, w_outT, b_out, x, out);
}

// Round 6
// 166.279 us; speedup vs baseline: 1.6504x; 1.0169x over previous
//
#include <hip/hip_runtime.h>
#include <hip/hip_bf16.h>

// B=2, C=256, N=4096, heads=4, D=64, 3D=192, M_embed=768
#define NH   4
#define D_   64
#define N_   4096
#define C_   256
#define ME   768
#define SPLITS 4
#define QSCALE 0.18033688f   // 0.125 * log2(e): softmax done in exp2 domain

typedef float    f32x4  __attribute__((ext_vector_type(4)));
typedef float    f32x16 __attribute__((ext_vector_type(16)));
typedef _Float16 f16x8  __attribute__((ext_vector_type(8)));
typedef _Float16 f16x4  __attribute__((ext_vector_type(4)));

// ---------------------------------------------------------------------------
// Prep (merged): blocks [0,512): x fp32 [b][c][n] -> xT f16 [b][n][c]
//                blocks [512,608): w_embed -> wh f16 copy
//                blocks [608,624): w_out [k][c] -> w_outT f16 [c][k]
// ---------------------------------------------------------------------------
__global__ __launch_bounds__(256) void prep_kernel(const float* __restrict__ x,
                                                   const float* __restrict__ w_embed,
                                                   const float* __restrict__ w_out,
                                                   _Float16* __restrict__ xT,
                                                   _Float16* __restrict__ wh,
                                                   _Float16* __restrict__ w_outT) {
    __shared__ float T[64][68];
    const int t = threadIdx.x, bx = blockIdx.x;
    if (bx < 512) {
        const int n0 = (bx & 63) * 64, c0 = ((bx >> 6) & 3) * 64, b = bx >> 8;
        const float* xp = x + ((size_t)b * C_ + c0) * N_ + n0;
        #pragma unroll
        for (int r = 0; r < 4; ++r) {
            int idx = r * 256 + t;
            int c = idx >> 4, ng = (idx & 15) * 4;
            *(f32x4*)&T[c][ng] = *(const f32x4*)(xp + (size_t)c * N_ + ng);
        }
        __syncthreads();
        _Float16* dp = xT + ((size_t)b * N_ + n0) * C_ + c0;
        #pragma unroll
        for (int r = 0; r < 2; ++r) {
            int idx = r * 256 + t;
            int n = idx >> 3, cg = (idx & 7) * 8;
            f16x8 v;
            #pragma unroll
            for (int j = 0; j < 8; ++j) v[j] = (_Float16)T[cg + j][n];
            *(f16x8*)(dp + (size_t)n * C_ + cg) = v;
        }
    } else if (bx < 608) {
        int gid = (bx - 512) * 256 + t;
        const float* s = w_embed + (size_t)gid * 8;
        f32x4 a = *(const f32x4*)s, b2 = *(const f32x4*)(s + 4);
        f16x8 v = { (_Float16)a[0], (_Float16)a[1], (_Float16)a[2], (_Float16)a[3],
                    (_Float16)b2[0], (_Float16)b2[1], (_Float16)b2[2], (_Float16)b2[3] };
        *(f16x8*)(wh + (size_t)gid * 8) = v;
    } else {
        int tile = bx - 608;
        int tc = tile & 3, tk = tile >> 2;
        #pragma unroll
        for (int r = 0; r < 4; ++r) {
            int idx = r * 256 + t;
            int kl = idx >> 4, cl = (idx & 15) * 4;
            *(f32x4*)&T[kl][cl] = *(const f32x4*)(w_out + (size_t)(tk * 64 + kl) * C_ + tc * 64 + cl);
        }
        __syncthreads();
        #pragma unroll
        for (int r = 0; r < 2; ++r) {
            int idx = r * 256 + t;
            int cl = idx >> 3, kg = (idx & 7) * 8;
            f16x8 v;
            #pragma unroll
            for (int j = 0; j < 8; ++j) v[j] = (_Float16)T[kg + j][cl];
            *(f16x8*)(w_outT + (size_t)(tc * 64 + cl) * C_ + tk * 64 + kg) = v;
        }
    }
}

// ---------------------------------------------------------------------------
// QKV GEMM (f16 MFMA 16x16x32), epilogue routes to qT/kT [n][d] or vB [d][n].
// q is written PRE-SCALED by QSCALE (softmax runs in exp2 domain downstream).
// ---------------------------------------------------------------------------
__global__ __launch_bounds__(256) void qkv_gemm(const _Float16* __restrict__ xT,
                                                const _Float16* __restrict__ wh,
                                                const float* __restrict__ b_embed,
                                                _Float16* __restrict__ qT,
                                                _Float16* __restrict__ kT,
                                                _Float16* __restrict__ vB) {
    __shared__ __align__(16) union SM {
        struct { _Float16 A[64][40], X[64][40]; } s;
        float Os[64][68];
    } sm;
    const int n0 = blockIdx.x * 64, mt = blockIdx.y, b = blockIdx.z;
    const int m0 = mt * 64;
    const int t = threadIdx.x;
    const int lane = t & 63, w = t >> 6, quad = lane >> 4, l16 = lane & 15;
    const int srow = t >> 2, skoff = (t & 3) * 8;
    const int h = mt / 3, r3 = mt - h * 3;
    const float oscale = (r3 == 0) ? QSCALE : 1.0f;
    f32x4 acc[4] = {};
    for (int k0 = 0; k0 < C_; k0 += 32) {
        __syncthreads();
        *(f16x8*)&sm.s.A[srow][skoff] = *(const f16x8*)(wh + (size_t)(m0 + srow) * C_ + k0 + skoff);
        *(f16x8*)&sm.s.X[srow][skoff] = *(const f16x8*)(xT + ((size_t)b * N_ + n0 + srow) * C_ + k0 + skoff);
        __syncthreads();
        f16x8 af = *(const f16x8*)&sm.s.A[w * 16 + l16][quad * 8];
        #pragma unroll
        for (int nb = 0; nb < 4; ++nb) {
            f16x8 bf = *(const f16x8*)&sm.s.X[nb * 16 + l16][quad * 8];
            acc[nb] = __builtin_amdgcn_mfma_f32_16x16x32_f16(af, bf, acc[nb], 0, 0, 0);
        }
    }
    float bias[4];
    #pragma unroll
    for (int rg = 0; rg < 4; ++rg) bias[rg] = b_embed[m0 + w * 16 + quad * 4 + rg];
    __syncthreads();
    #pragma unroll
    for (int nb = 0; nb < 4; ++nb)
        #pragma unroll
        for (int rg = 0; rg < 4; ++rg)
            sm.Os[w * 16 + quad * 4 + rg][nb * 16 + l16] = (acc[nb][rg] + bias[rg]) * oscale;
    __syncthreads();
    const int bh = b * NH + h;
    if (r3 < 2) {
        _Float16* dst = (r3 ? kT : qT) + ((size_t)bh * N_ + n0) * D_;
        #pragma unroll
        for (int r = 0; r < 2; ++r) {
            int idx = r * 256 + t;
            int n = idx >> 3, mg = (idx & 7) * 8;
            f16x8 v;
            #pragma unroll
            for (int j = 0; j < 8; ++j) v[j] = (_Float16)sm.Os[mg + j][n];
            *(f16x8*)(dst + (size_t)n * D_ + mg) = v;
        }
    } else {
        _Float16* dst = vB + (size_t)bh * D_ * N_ + n0;
        #pragma unroll
        for (int r = 0; r < 2; ++r) {
            int idx = r * 256 + t;
            int d = idx >> 3, ng = (idx & 7) * 8;
            f32x4 a = *(const f32x4*)&sm.Os[d][ng];
            f32x4 b2 = *(const f32x4*)&sm.Os[d][ng + 4];
            f16x8 v = { (_Float16)a[0], (_Float16)a[1], (_Float16)a[2], (_Float16)a[3],
                        (_Float16)b2[0], (_Float16)b2[1], (_Float16)b2[2], (_Float16)b2[3] };
            *(f16x8*)(dst + (size_t)d * N_ + ng) = v;
        }
    }
}

// ---------------------------------------------------------------------------
// Flash attention v4: 32x32x16 MFMA, block = 128 i x 64 j, 4 waves x 32 i.
// Double-buffered K/V LDS -> ONE barrier per iter. Q pre-scaled upstream.
// P built in registers from St C-layout via shfl_xor(32); cvt_pkrtz packing.
// Split-KV x4 (grid 1024 = 4 blocks/CU). __launch_bounds__(256,4) caps VGPR@128.
// ---------------------------------------------------------------------------
__global__ __launch_bounds__(256, 4) void attn_kernel(const _Float16* __restrict__ qT,
                                                      const _Float16* __restrict__ kT,
                                                      const _Float16* __restrict__ vB,
                                                      _Float16* __restrict__ opart,
                                                      float* __restrict__ mpart,
                                                      float* __restrict__ lpart) {
    __shared__ __align__(16) union SM {
        struct { _Float16 K[2][64][76], V[2][64][76]; } s;   // 38912 B
        _Float16 Os[128][76];
    } sm;
    const int t = threadIdx.x;
    const int qt = blockIdx.x, h = blockIdx.y;
    const int b = blockIdx.z >> 2, s = blockIdx.z & 3;
    const int bh = b * NH + h, sbh = s * 8 + bh;
    const _Float16* kp = kT + (size_t)bh * N_ * D_;   // [j][d]
    const _Float16* vp = vB + (size_t)bh * D_ * N_;   // [d][n]
    const int lane = t & 63, w = t >> 6, l32 = lane & 31, hl = lane >> 5;
    const bool hl1 = (hl != 0);
    const int srow = t >> 3, scol = (t & 7) * 8;       // rows srow, srow+32

    // Q B-frags in registers (already scaled by QSCALE in qkv epilogue)
    const _Float16* qp = qT + ((size_t)bh * N_ + qt * 128 + w * 32 + l32) * D_;
    f16x8 qf[4];
    #pragma unroll
    for (int kc = 0; kc < 4; ++kc) qf[kc] = *(const f16x8*)(qp + kc * 16 + hl * 8);

    f32x16 oacc0 = {}, oacc1 = {};
    float m_run = -3.0e38f, l_run = 0.f;

    const int jt_lo = s * 16, jt_hi = jt_lo + 16;
    f16x8 kpre[2], vpre[2];
    #pragma unroll
    for (int r = 0; r < 2; ++r) {
        int row = srow + r * 32;
        kpre[r] = *(const f16x8*)(kp + (size_t)(jt_lo * 64 + row) * D_ + scol);
        vpre[r] = *(const f16x8*)(vp + (size_t)row * N_ + jt_lo * 64 + scol);
    }
    #pragma unroll
    for (int r = 0; r < 2; ++r) {        // prologue: fill buf 0
        int row = srow + r * 32;
        *(f16x8*)&sm.s.K[0][row][scol] = kpre[r];
        *(f16x8*)&sm.s.V[0][row][scol] = vpre[r];
    }

    int buf = 0;
    for (int jt = jt_lo; jt < jt_hi; ++jt) {
        __syncthreads();   // buf is ready; previous buf^1 reads all done
        const bool more = (jt + 1 < jt_hi);
        if (more) {
            #pragma unroll
            for (int r = 0; r < 2; ++r) {
                int row = srow + r * 32;
                kpre[r] = *(const f16x8*)(kp + (size_t)((jt + 1) * 64 + row) * D_ + scol);
                vpre[r] = *(const f16x8*)(vp + (size_t)row * N_ + (jt + 1) * 64 + scol);
            }
        }

        // ---- St = K Q^T : two 32x32 tiles
        f32x16 sa0 = {}, sa1 = {};
        #pragma unroll
        for (int kc = 0; kc < 4; ++kc) {
            f16x8 kf0 = *(const f16x8*)&sm.s.K[buf][l32][kc * 16 + hl * 8];
            sa0 = __builtin_amdgcn_mfma_f32_32x32x16_f16(kf0, qf[kc], sa0, 0, 0, 0);
            f16x8 kf1 = *(const f16x8*)&sm.s.K[buf][32 + l32][kc * 16 + hl * 8];
            sa1 = __builtin_amdgcn_mfma_f32_32x32x16_f16(kf1, qf[kc], sa1, 0, 0, 0);
        }

        // ---- online softmax (exp2 domain)
        f32x16 mm;
        #pragma unroll
        for (int r = 0; r < 16; ++r) mm[r] = fmaxf(sa0[r], sa1[r]);
        f32x4 m4;
        #pragma unroll
        for (int r = 0; r < 4; ++r)
            m4[r] = fmaxf(fmaxf(mm[r], mm[r + 4]), fmaxf(mm[r + 8], mm[r + 12]));
        float mx = fmaxf(fmaxf(m4[0], m4[1]), fmaxf(m4[2], m4[3]));
        mx = fmaxf(mx, __shfl_xor(mx, 32));
        float mnew  = fmaxf(m_run, mx);
        float alpha = exp2f(m_run - mnew);
        #pragma unroll
        for (int r = 0; r < 16; ++r) sa0[r] = exp2f(sa0[r] - mnew);
        #pragma unroll
        for (int r = 0; r < 16; ++r) sa1[r] = exp2f(sa1[r] - mnew);
        f32x16 sv = sa0 + sa1;
        f32x4 s4;
        #pragma unroll
        for (int r = 0; r < 4; ++r) s4[r] = (sv[r] + sv[r + 4]) + (sv[r + 8] + sv[r + 12]);
        float rs = (s4[0] + s4[1]) + (s4[2] + s4[3]);
        rs += __shfl_xor(rs, 32);
        l_run = l_run * alpha + rs;
        m_run = mnew;
        oacc0 *= alpha;
        oacc1 *= alpha;

        // ---- P -> B-frags in registers; Ot += Vt * P
        #pragma unroll
        for (int jb = 0; jb < 2; ++jb) {
            const f32x16& sa = jb ? sa1 : sa0;
            int P[8], X[8];
            #pragma unroll
            for (int q = 0; q < 8; ++q)
                P[q] = __builtin_bit_cast(int, __builtin_amdgcn_cvt_pkrtz(sa[2 * q], sa[2 * q + 1]));
            #pragma unroll
            for (int q = 0; q < 8; ++q) X[q] = __shfl_xor(P[q], 32);
            union FU { f16x8 v; int d[4]; } f0, f1;
            f0.d[0] = hl1 ? X[2] : P[0];
            f0.d[1] = hl1 ? X[3] : P[1];
            f0.d[2] = hl1 ? P[2] : X[0];
            f0.d[3] = hl1 ? P[3] : X[1];
            f1.d[0] = hl1 ? X[6] : P[4];
            f1.d[1] = hl1 ? X[7] : P[5];
            f1.d[2] = hl1 ? P[6] : X[4];
            f1.d[3] = hl1 ? P[7] : X[5];
            f16x8 vf = *(const f16x8*)&sm.s.V[buf][l32][jb * 32 + hl * 8];
            oacc0 = __builtin_amdgcn_mfma_f32_32x32x16_f16(vf, f0.v, oacc0, 0, 0, 0);
            vf = *(const f16x8*)&sm.s.V[buf][l32][jb * 32 + 16 + hl * 8];
            oacc0 = __builtin_amdgcn_mfma_f32_32x32x16_f16(vf, f1.v, oacc0, 0, 0, 0);
            vf = *(const f16x8*)&sm.s.V[buf][32 + l32][jb * 32 + hl * 8];
            oacc1 = __builtin_amdgcn_mfma_f32_32x32x16_f16(vf, f0.v, oacc1, 0, 0, 0);
            vf = *(const f16x8*)&sm.s.V[buf][32 + l32][jb * 32 + 16 + hl * 8];
            oacc1 = __builtin_amdgcn_mfma_f32_32x32x16_f16(vf, f1.v, oacc1, 0, 0, 0);
        }

        // ---- stage next tile into the other buffer (no barrier needed here)
        if (more) {
            #pragma unroll
            for (int r = 0; r < 2; ++r) {
                int row = srow + r * 32;
                *(f16x8*)&sm.s.K[buf ^ 1][row][scol] = kpre[r];
                *(f16x8*)&sm.s.V[buf ^ 1][row][scol] = vpre[r];
            }
        }
        buf ^= 1;
    }

    // ---- epilogue: per-split normalized O (f16) + m,l
    float linv = 1.f / l_run;
    if (hl == 0) {
        mpart[(size_t)sbh * N_ + qt * 128 + w * 32 + l32] = m_run;
        lpart[(size_t)sbh * N_ + qt * 128 + w * 32 + l32] = l_run;
    }
    __syncthreads();
    #pragma unroll
    for (int db = 0; db < 2; ++db) {
        const f32x16& oc = db ? oacc1 : oacc0;
        #pragma unroll
        for (int rq = 0; rq < 4; ++rq) {
            f16x4 pv = { (_Float16)(oc[rq * 4 + 0] * linv), (_Float16)(oc[rq * 4 + 1] * linv),
                         (_Float16)(oc[rq * 4 + 2] * linv), (_Float16)(oc[rq * 4 + 3] * linv) };
            *(f16x4*)&sm.Os[w * 32 + l32][db * 32 + rq * 8 + hl * 4] = pv;
        }
    }
    __syncthreads();
    _Float16* op = opart + ((size_t)sbh * N_ + qt * 128) * D_;
    #pragma unroll
    for (int r = 0; r < 4; ++r) {
        int idx = r * 256 + t;
        int i = idx >> 3, ch = (idx & 7) * 8;
        *(f16x8*)(op + (size_t)i * D_ + ch) = *(const f16x8*)&sm.Os[i][ch];
    }
}

// ---------------------------------------------------------------------------
// Output projection + FUSED split-KV combine + bias + residual.
// Phase 0: per-(h, n) combine weights W[h][n][s] = exp2(m_s - M) * l_s / sum.
// Y-staging combines 4 opart streams on the fly; then f16 MFMA; epilogue adds
// bias + x residual.
// ---------------------------------------------------------------------------
__global__ __launch_bounds__(256) void proj_gemm(const _Float16* __restrict__ opart,
                                                 const float* __restrict__ mpart,
                                                 const float* __restrict__ lpart,
                                                 const _Float16* __restrict__ w_outT,
                                                 const float* __restrict__ b_out,
                                                 const float* __restrict__ x,
                                                 float* __restrict__ out) {
    __shared__ __align__(16) union SM {
        struct { _Float16 A[64][40], Y[64][40]; float W[4][64][4]; } s;
        float Os[64][68];
    } sm;
    const int n0 = blockIdx.x * 64, c0 = blockIdx.y * 64, b = blockIdx.z;
    const int t = threadIdx.x;
    const int lane = t & 63, w = t >> 6, quad = lane >> 4, l16 = lane & 15;
    const int srow = t >> 2, skoff = (t & 3) * 8;

    // phase 0: combine weights for this block's 64 n-rows x 4 heads
    {
        const int nl = t & 63, hh = t >> 6;
        const int bh = b * NH + hh;
        float mv[4], lv[4];
        #pragma unroll
        for (int sI = 0; sI < 4; ++sI) {
            mv[sI] = mpart[(size_t)(sI * 8 + bh) * N_ + n0 + nl];
            lv[sI] = lpart[(size_t)(sI * 8 + bh) * N_ + n0 + nl];
        }
        float M = fmaxf(fmaxf(mv[0], mv[1]), fmaxf(mv[2], mv[3]));
        float ws[4], sum = 0.f;
        #pragma unroll
        for (int sI = 0; sI < 4; ++sI) { ws[sI] = exp2f(mv[sI] - M) * lv[sI]; sum += ws[sI]; }
        float inv = 1.f / sum;
        #pragma unroll
        for (int sI = 0; sI < 4; ++sI) sm.s.W[hh][nl][sI] = ws[sI] * inv;
    }

    f32x4 acc[4] = {};
    for (int k0 = 0; k0 < C_; k0 += 32) {
        __syncthreads();
        *(f16x8*)&sm.s.A[srow][skoff] = *(const f16x8*)(w_outT + (size_t)(c0 + srow) * C_ + k0 + skoff);
        {   // combine-on-the-fly Y staging: k = k0+skoff -> head hh, d-offset d0
            const int k = k0 + skoff;
            const int hh = k >> 6, d0 = k & 63;
            const int bh = b * NH + hh;
            const float* Wn = &sm.s.W[hh][srow][0];
            float accf[8] = {};
            #pragma unroll
            for (int sI = 0; sI < 4; ++sI) {
                f16x8 ov = *(const f16x8*)(opart + ((size_t)(sI * 8 + bh) * N_ + n0 + srow) * D_ + d0);
                float wsv = Wn[sI];
                #pragma unroll
                for (int j = 0; j < 8; ++j) accf[j] += wsv * (float)ov[j];
            }
            f16x8 yv;
            #pragma unroll
            for (int j = 0; j < 8; ++j) yv[j] = (_Float16)accf[j];
            *(f16x8*)&sm.s.Y[srow][skoff] = yv;
        }
        __syncthreads();
        f16x8 af = *(const f16x8*)&sm.s.A[w * 16 + l16][quad * 8];
        #pragma unroll
        for (int nb = 0; nb < 4; ++nb) {
            f16x8 bf = *(const f16x8*)&sm.s.Y[nb * 16 + l16][quad * 8];
            acc[nb] = __builtin_amdgcn_mfma_f32_16x16x32_f16(af, bf, acc[nb], 0, 0, 0);
        }
    }
    float bias[4];
    #pragma unroll
    for (int rg = 0; rg < 4; ++rg) bias[rg] = b_out[c0 + w * 16 + quad * 4 + rg];
    __syncthreads();
    #pragma unroll
    for (int nb = 0; nb < 4; ++nb)
        #pragma unroll
        for (int rg = 0; rg < 4; ++rg)
            sm.Os[w * 16 + quad * 4 + rg][nb * 16 + l16] = acc[nb][rg] + bias[rg];
    __syncthreads();
    const float* xp = x + ((size_t)b * C_ + c0) * N_ + n0;
    float* op = out + ((size_t)b * C_ + c0) * N_ + n0;
    #pragma unroll
    for (int r = 0; r < 4; ++r) {
        int idx = r * 256 + t;
        int c = idx >> 4, ng = (idx & 15) * 4;
        f32x4 v  = *(const f32x4*)&sm.Os[c][ng];
        f32x4 xv = *(const f32x4*)(xp + (size_t)c * N_ + ng);
        f32x4 o  = { v[0] + xv[0], v[1] + xv[1], v[2] + xv[2], v[3] + xv[3] };
        *(f32x4*)(op + (size_t)c * N_ + ng) = o;
    }
}

// ---------------------------------------------------------------------------
// Workspace map (f16 element offsets; total ~35.1 MB):
//   xT 0 (2,097,152) | wh 2,097,152 (196,608) | w_outT 2,293,760 (65,536)
//   qT 2,359,296 | kT 4,456,448 | vB 6,553,600 (2,097,152 each)
//   opart 8,650,752 (8,388,608 = 4 splits x 8 bh x 4096 x 64)
//   mpart f32 @ +17,039,360 (131,072) ; lpart follows
// ---------------------------------------------------------------------------
extern "C" void kernel_launch(void* const* d_in, const int* in_sizes, int n_in,
                              void* d_out, int out_size, void* d_ws, size_t ws_size,
                              hipStream_t stream) {
    const float* x       = (const float*)d_in[0];
    const float* w_embed = (const float*)d_in[1];
    const float* b_embed = (const float*)d_in[2];
    const float* w_out   = (const float*)d_in[3];
    const float* b_out   = (const float*)d_in[4];
    float* out = (float*)d_out;

    _Float16* base   = (_Float16*)d_ws;
    _Float16* xT     = base;
    _Float16* wh     = base + 2097152;
    _Float16* w_outT = base + 2293760;
    _Float16* qT     = base + 2359296;
    _Float16* kT     = base + 4456448;
    _Float16* vB     = base + 6553600;
    _Float16* opart  = base + 8650752;
    float*    mpart  = (float*)(base + 17039360);
    float*    lpart  = mpart + 131072;

    prep_kernel<<<dim3(624, 1, 1), 256, 0, stream>>>(x, w_embed, w_out, xT, wh, w_outT);
    qkv_gemm   <<<dim3(64, 12, 2), 256, 0, stream>>>(xT, wh, b_embed, qT, kT, vB);
    attn_kernel<<<dim3(32, 4, 8),  256, 0, stream>>>(qT, kT, vB, opart, mpart, lpart);
    proj_gemm  <<<dim3(64, 4, 2),  256, 0, stream>>>(opart, mpart, lpart, w_outT, b_out, x, out);
}

// Round 7
// 153.600 us; speedup vs baseline: 1.7867x; 1.0825x over previous
//
#include <hip/hip_runtime.h>
#include <hip/hip_bf16.h>

// B=2, C=256, N=4096, heads=4, D=64, 3D=192, M_embed=768
#define NH   4
#define D_   64
#define N_   4096
#define C_   256
#define ME   768
#define QSCALE 0.18033688f   // 0.125 * log2(e): softmax done in exp2 domain

typedef float    f32x4  __attribute__((ext_vector_type(4)));
typedef float    f32x16 __attribute__((ext_vector_type(16)));
typedef _Float16 f16x8  __attribute__((ext_vector_type(8)));
typedef _Float16 f16x4  __attribute__((ext_vector_type(4)));

// ---------------------------------------------------------------------------
// Prep (merged): blocks [0,512): x fp32 [b][c][n] -> xT f16 [b][n][c]
//                blocks [512,608): w_embed -> wh f16 copy
//                blocks [608,624): w_out [k][c] -> w_outT f16 [c][k]
// ---------------------------------------------------------------------------
__global__ __launch_bounds__(256) void prep_kernel(const float* __restrict__ x,
                                                   const float* __restrict__ w_embed,
                                                   const float* __restrict__ w_out,
                                                   _Float16* __restrict__ xT,
                                                   _Float16* __restrict__ wh,
                                                   _Float16* __restrict__ w_outT) {
    __shared__ float T[64][68];
    const int t = threadIdx.x, bx = blockIdx.x;
    if (bx < 512) {
        const int n0 = (bx & 63) * 64, c0 = ((bx >> 6) & 3) * 64, b = bx >> 8;
        const float* xp = x + ((size_t)b * C_ + c0) * N_ + n0;
        #pragma unroll
        for (int r = 0; r < 4; ++r) {
            int idx = r * 256 + t;
            int c = idx >> 4, ng = (idx & 15) * 4;
            *(f32x4*)&T[c][ng] = *(const f32x4*)(xp + (size_t)c * N_ + ng);
        }
        __syncthreads();
        _Float16* dp = xT + ((size_t)b * N_ + n0) * C_ + c0;
        #pragma unroll
        for (int r = 0; r < 2; ++r) {
            int idx = r * 256 + t;
            int n = idx >> 3, cg = (idx & 7) * 8;
            f16x8 v;
            #pragma unroll
            for (int j = 0; j < 8; ++j) v[j] = (_Float16)T[cg + j][n];
            *(f16x8*)(dp + (size_t)n * C_ + cg) = v;
        }
    } else if (bx < 608) {
        int gid = (bx - 512) * 256 + t;
        const float* s = w_embed + (size_t)gid * 8;
        f32x4 a = *(const f32x4*)s, b2 = *(const f32x4*)(s + 4);
        f16x8 v = { (_Float16)a[0], (_Float16)a[1], (_Float16)a[2], (_Float16)a[3],
                    (_Float16)b2[0], (_Float16)b2[1], (_Float16)b2[2], (_Float16)b2[3] };
        *(f16x8*)(wh + (size_t)gid * 8) = v;
    } else {
        int tile = bx - 608;
        int tc = tile & 3, tk = tile >> 2;
        #pragma unroll
        for (int r = 0; r < 4; ++r) {
            int idx = r * 256 + t;
            int kl = idx >> 4, cl = (idx & 15) * 4;
            *(f32x4*)&T[kl][cl] = *(const f32x4*)(w_out + (size_t)(tk * 64 + kl) * C_ + tc * 64 + cl);
        }
        __syncthreads();
        #pragma unroll
        for (int r = 0; r < 2; ++r) {
            int idx = r * 256 + t;
            int cl = idx >> 3, kg = (idx & 7) * 8;
            f16x8 v;
            #pragma unroll
            for (int j = 0; j < 8; ++j) v[j] = (_Float16)T[kg + j][cl];
            *(f16x8*)(w_outT + (size_t)(tc * 64 + cl) * C_ + tk * 64 + kg) = v;
        }
    }
}

// ---------------------------------------------------------------------------
// QKV GEMM (f16 MFMA 16x16x32), epilogue routes to qT/kT [n][d] or vB [d][n].
// q is written PRE-SCALED by QSCALE (softmax runs in exp2 domain downstream).
// ---------------------------------------------------------------------------
__global__ __launch_bounds__(256) void qkv_gemm(const _Float16* __restrict__ xT,
                                                const _Float16* __restrict__ wh,
                                                const float* __restrict__ b_embed,
                                                _Float16* __restrict__ qT,
                                                _Float16* __restrict__ kT,
                                                _Float16* __restrict__ vB) {
    __shared__ __align__(16) union SM {
        struct { _Float16 A[64][40], X[64][40]; } s;
        float Os[64][68];
    } sm;
    const int n0 = blockIdx.x * 64, mt = blockIdx.y, b = blockIdx.z;
    const int m0 = mt * 64;
    const int t = threadIdx.x;
    const int lane = t & 63, w = t >> 6, quad = lane >> 4, l16 = lane & 15;
    const int srow = t >> 2, skoff = (t & 3) * 8;
    const int h = mt / 3, r3 = mt - h * 3;
    const float oscale = (r3 == 0) ? QSCALE : 1.0f;
    f32x4 acc[4] = {};
    for (int k0 = 0; k0 < C_; k0 += 32) {
        __syncthreads();
        *(f16x8*)&sm.s.A[srow][skoff] = *(const f16x8*)(wh + (size_t)(m0 + srow) * C_ + k0 + skoff);
        *(f16x8*)&sm.s.X[srow][skoff] = *(const f16x8*)(xT + ((size_t)b * N_ + n0 + srow) * C_ + k0 + skoff);
        __syncthreads();
        f16x8 af = *(const f16x8*)&sm.s.A[w * 16 + l16][quad * 8];
        #pragma unroll
        for (int nb = 0; nb < 4; ++nb) {
            f16x8 bf = *(const f16x8*)&sm.s.X[nb * 16 + l16][quad * 8];
            acc[nb] = __builtin_amdgcn_mfma_f32_16x16x32_f16(af, bf, acc[nb], 0, 0, 0);
        }
    }
    float bias[4];
    #pragma unroll
    for (int rg = 0; rg < 4; ++rg) bias[rg] = b_embed[m0 + w * 16 + quad * 4 + rg];
    __syncthreads();
    #pragma unroll
    for (int nb = 0; nb < 4; ++nb)
        #pragma unroll
        for (int rg = 0; rg < 4; ++rg)
            sm.Os[w * 16 + quad * 4 + rg][nb * 16 + l16] = (acc[nb][rg] + bias[rg]) * oscale;
    __syncthreads();
    const int bh = b * NH + h;
    if (r3 < 2) {
        _Float16* dst = (r3 ? kT : qT) + ((size_t)bh * N_ + n0) * D_;
        #pragma unroll
        for (int r = 0; r < 2; ++r) {
            int idx = r * 256 + t;
            int n = idx >> 3, mg = (idx & 7) * 8;
            f16x8 v;
            #pragma unroll
            for (int j = 0; j < 8; ++j) v[j] = (_Float16)sm.Os[mg + j][n];
            *(f16x8*)(dst + (size_t)n * D_ + mg) = v;
        }
    } else {
        _Float16* dst = vB + (size_t)bh * D_ * N_ + n0;
        #pragma unroll
        for (int r = 0; r < 2; ++r) {
            int idx = r * 256 + t;
            int d = idx >> 3, ng = (idx & 7) * 8;
            f32x4 a = *(const f32x4*)&sm.Os[d][ng];
            f32x4 b2 = *(const f32x4*)&sm.Os[d][ng + 4];
            f16x8 v = { (_Float16)a[0], (_Float16)a[1], (_Float16)a[2], (_Float16)a[3],
                        (_Float16)b2[0], (_Float16)b2[1], (_Float16)b2[2], (_Float16)b2[3] };
            *(f16x8*)(dst + (size_t)d * N_ + ng) = v;
        }
    }
}

// ---------------------------------------------------------------------------
// Flash attention v5: St = K*Q^T via 32x32x16 (A=K LDS, B=Q regs).
// PV via 32x32x8f16 ZERO-SHUFFLE trick: the 32x32 C-layout dword pair
// (P[2c],P[2c+1]) = rows c*8 + hl*4 + (0..3) is EXACTLY the x8 B-frag
// B[k=hl*4+j] for k-chunk c -> each lane feeds its own St C-regs into 16
// x8 MFMAs; no bpermute, no cndmask. exp2 via __builtin_amdgcn_exp2f.
// Double-buffered K/V LDS, one barrier/iter. Split-KV x4 (grid 1024).
// ---------------------------------------------------------------------------
__global__ __launch_bounds__(256, 4) void attn_kernel(const _Float16* __restrict__ qT,
                                                      const _Float16* __restrict__ kT,
                                                      const _Float16* __restrict__ vB,
                                                      _Float16* __restrict__ opart,
                                                      float* __restrict__ mpart,
                                                      float* __restrict__ lpart) {
    __shared__ __align__(16) union SM {
        struct { _Float16 K[2][64][76], V[2][64][76]; } s;   // 38912 B
        _Float16 Os[128][76];
    } sm;
    const int t = threadIdx.x;
    const int qt = blockIdx.x, h = blockIdx.y;
    const int b = blockIdx.z >> 2, s = blockIdx.z & 3;
    const int bh = b * NH + h, sbh = s * 8 + bh;
    const _Float16* kp = kT + (size_t)bh * N_ * D_;   // [j][d]
    const _Float16* vp = vB + (size_t)bh * D_ * N_;   // [d][n]
    const int lane = t & 63, w = t >> 6, l32 = lane & 31, hl = lane >> 5;
    const int srow = t >> 3, scol = (t & 7) * 8;       // rows srow, srow+32

    // Q B-frags in registers (already scaled by QSCALE in qkv epilogue)
    const _Float16* qp = qT + ((size_t)bh * N_ + qt * 128 + w * 32 + l32) * D_;
    f16x8 qf[4];
    #pragma unroll
    for (int kc = 0; kc < 4; ++kc) qf[kc] = *(const f16x8*)(qp + kc * 16 + hl * 8);

    f32x16 oacc0 = {}, oacc1 = {};
    float m_run = -3.0e38f, l_run = 0.f;

    const int jt_lo = s * 16, jt_hi = jt_lo + 16;
    f16x8 kpre[2], vpre[2];
    #pragma unroll
    for (int r = 0; r < 2; ++r) {
        int row = srow + r * 32;
        kpre[r] = *(const f16x8*)(kp + (size_t)(jt_lo * 64 + row) * D_ + scol);
        vpre[r] = *(const f16x8*)(vp + (size_t)row * N_ + jt_lo * 64 + scol);
    }
    #pragma unroll
    for (int r = 0; r < 2; ++r) {        // prologue: fill buf 0
        int row = srow + r * 32;
        *(f16x8*)&sm.s.K[0][row][scol] = kpre[r];
        *(f16x8*)&sm.s.V[0][row][scol] = vpre[r];
    }

    int buf = 0;
    for (int jt = jt_lo; jt < jt_hi; ++jt) {
        __syncthreads();   // buf is ready; previous buf^1 reads all done
        const bool more = (jt + 1 < jt_hi);
        if (more) {
            #pragma unroll
            for (int r = 0; r < 2; ++r) {
                int row = srow + r * 32;
                kpre[r] = *(const f16x8*)(kp + (size_t)((jt + 1) * 64 + row) * D_ + scol);
                vpre[r] = *(const f16x8*)(vp + (size_t)row * N_ + (jt + 1) * 64 + scol);
            }
        }

        // ---- St = K Q^T : two 32x32 tiles
        f32x16 sa0 = {}, sa1 = {};
        #pragma unroll
        for (int kc = 0; kc < 4; ++kc) {
            f16x8 kf0 = *(const f16x8*)&sm.s.K[buf][l32][kc * 16 + hl * 8];
            sa0 = __builtin_amdgcn_mfma_f32_32x32x16_f16(kf0, qf[kc], sa0, 0, 0, 0);
            f16x8 kf1 = *(const f16x8*)&sm.s.K[buf][32 + l32][kc * 16 + hl * 8];
            sa1 = __builtin_amdgcn_mfma_f32_32x32x16_f16(kf1, qf[kc], sa1, 0, 0, 0);
        }

        // ---- online softmax (exp2 domain, raw v_exp_f32 via builtin)
        f32x16 mm;
        #pragma unroll
        for (int r = 0; r < 16; ++r) mm[r] = fmaxf(sa0[r], sa1[r]);
        f32x4 m4;
        #pragma unroll
        for (int r = 0; r < 4; ++r)
            m4[r] = fmaxf(fmaxf(mm[r], mm[r + 4]), fmaxf(mm[r + 8], mm[r + 12]));
        float mx = fmaxf(fmaxf(m4[0], m4[1]), fmaxf(m4[2], m4[3]));
        mx = fmaxf(mx, __shfl_xor(mx, 32));
        float mnew  = fmaxf(m_run, mx);
        float alpha = __builtin_amdgcn_exp2f(m_run - mnew);
        #pragma unroll
        for (int r = 0; r < 16; ++r) sa0[r] = __builtin_amdgcn_exp2f(sa0[r] - mnew);
        #pragma unroll
        for (int r = 0; r < 16; ++r) sa1[r] = __builtin_amdgcn_exp2f(sa1[r] - mnew);
        f32x16 sv = sa0 + sa1;
        f32x4 s4;
        #pragma unroll
        for (int r = 0; r < 4; ++r) s4[r] = (sv[r] + sv[r + 4]) + (sv[r + 8] + sv[r + 12]);
        float rs = (s4[0] + s4[1]) + (s4[2] + s4[3]);
        rs += __shfl_xor(rs, 32);
        l_run = l_run * alpha + rs;
        m_run = mnew;
        oacc0 *= alpha;
        oacc1 *= alpha;

        // ---- PV via 32x32x8f16: own C-regs ARE the B-frags (no exchange)
        #pragma unroll
        for (int jb = 0; jb < 2; ++jb) {
            const f32x16& sa = jb ? sa1 : sa0;
            union BU { f16x4 v; int d[2]; } bf[4];
            #pragma unroll
            for (int q = 0; q < 8; ++q)
                bf[q >> 1].d[q & 1] =
                    __builtin_bit_cast(int, __builtin_amdgcn_cvt_pkrtz(sa[2 * q], sa[2 * q + 1]));
            #pragma unroll
            for (int c = 0; c < 4; ++c) {
                const int vcol = jb * 32 + c * 8 + hl * 4;
                f16x4 va = *(const f16x4*)&sm.s.V[buf][l32][vcol];
                oacc0 = __builtin_amdgcn_mfma_f32_32x32x8f16(va, bf[c].v, oacc0, 0, 0, 0);
                f16x4 vb = *(const f16x4*)&sm.s.V[buf][32 + l32][vcol];
                oacc1 = __builtin_amdgcn_mfma_f32_32x32x8f16(vb, bf[c].v, oacc1, 0, 0, 0);
            }
        }

        // ---- stage next tile into the other buffer (no barrier needed here)
        if (more) {
            #pragma unroll
            for (int r = 0; r < 2; ++r) {
                int row = srow + r * 32;
                *(f16x8*)&sm.s.K[buf ^ 1][row][scol] = kpre[r];
                *(f16x8*)&sm.s.V[buf ^ 1][row][scol] = vpre[r];
            }
        }
        buf ^= 1;
    }

    // ---- epilogue: per-split normalized O (f16) + m,l
    float linv = 1.f / l_run;
    if (hl == 0) {
        mpart[(size_t)sbh * N_ + qt * 128 + w * 32 + l32] = m_run;
        lpart[(size_t)sbh * N_ + qt * 128 + w * 32 + l32] = l_run;
    }
    __syncthreads();
    #pragma unroll
    for (int db = 0; db < 2; ++db) {
        const f32x16& oc = db ? oacc1 : oacc0;
        #pragma unroll
        for (int rq = 0; rq < 4; ++rq) {
            f16x4 pv = { (_Float16)(oc[rq * 4 + 0] * linv), (_Float16)(oc[rq * 4 + 1] * linv),
                         (_Float16)(oc[rq * 4 + 2] * linv), (_Float16)(oc[rq * 4 + 3] * linv) };
            *(f16x4*)&sm.Os[w * 32 + l32][db * 32 + rq * 8 + hl * 4] = pv;
        }
    }
    __syncthreads();
    _Float16* op = opart + ((size_t)sbh * N_ + qt * 128) * D_;
    #pragma unroll
    for (int r = 0; r < 4; ++r) {
        int idx = r * 256 + t;
        int i = idx >> 3, ch = (idx & 7) * 8;
        *(f16x8*)(op + (size_t)i * D_ + ch) = *(const f16x8*)&sm.Os[i][ch];
    }
}

// ---------------------------------------------------------------------------
// Output projection + FUSED split-KV combine + bias + residual.
// ---------------------------------------------------------------------------
__global__ __launch_bounds__(256) void proj_gemm(const _Float16* __restrict__ opart,
                                                 const float* __restrict__ mpart,
                                                 const float* __restrict__ lpart,
                                                 const _Float16* __restrict__ w_outT,
                                                 const float* __restrict__ b_out,
                                                 const float* __restrict__ x,
                                                 float* __restrict__ out) {
    __shared__ __align__(16) union SM {
        struct { _Float16 A[64][40], Y[64][40]; float W[4][64][4]; } s;
        float Os[64][68];
    } sm;
    const int n0 = blockIdx.x * 64, c0 = blockIdx.y * 64, b = blockIdx.z;
    const int t = threadIdx.x;
    const int lane = t & 63, w = t >> 6, quad = lane >> 4, l16 = lane & 15;
    const int srow = t >> 2, skoff = (t & 3) * 8;

    // phase 0: combine weights for this block's 64 n-rows x 4 heads
    {
        const int nl = t & 63, hh = t >> 6;
        const int bh = b * NH + hh;
        float mv[4], lv[4];
        #pragma unroll
        for (int sI = 0; sI < 4; ++sI) {
            mv[sI] = mpart[(size_t)(sI * 8 + bh) * N_ + n0 + nl];
            lv[sI] = lpart[(size_t)(sI * 8 + bh) * N_ + n0 + nl];
        }
        float M = fmaxf(fmaxf(mv[0], mv[1]), fmaxf(mv[2], mv[3]));
        float ws[4], sum = 0.f;
        #pragma unroll
        for (int sI = 0; sI < 4; ++sI) {
            ws[sI] = __builtin_amdgcn_exp2f(mv[sI] - M) * lv[sI];
            sum += ws[sI];
        }
        float inv = 1.f / sum;
        #pragma unroll
        for (int sI = 0; sI < 4; ++sI) sm.s.W[hh][nl][sI] = ws[sI] * inv;
    }

    f32x4 acc[4] = {};
    for (int k0 = 0; k0 < C_; k0 += 32) {
        __syncthreads();
        *(f16x8*)&sm.s.A[srow][skoff] = *(const f16x8*)(w_outT + (size_t)(c0 + srow) * C_ + k0 + skoff);
        {   // combine-on-the-fly Y staging
            const int k = k0 + skoff;
            const int hh = k >> 6, d0 = k & 63;
            const int bh = b * NH + hh;
            const float* Wn = &sm.s.W[hh][srow][0];
            float accf[8] = {};
            #pragma unroll
            for (int sI = 0; sI < 4; ++sI) {
                f16x8 ov = *(const f16x8*)(opart + ((size_t)(sI * 8 + bh) * N_ + n0 + srow) * D_ + d0);
                float wsv = Wn[sI];
                #pragma unroll
                for (int j = 0; j < 8; ++j) accf[j] += wsv * (float)ov[j];
            }
            f16x8 yv;
            #pragma unroll
            for (int j = 0; j < 8; ++j) yv[j] = (_Float16)accf[j];
            *(f16x8*)&sm.s.Y[srow][skoff] = yv;
        }
        __syncthreads();
        f16x8 af = *(const f16x8*)&sm.s.A[w * 16 + l16][quad * 8];
        #pragma unroll
        for (int nb = 0; nb < 4; ++nb) {
            f16x8 bf = *(const f16x8*)&sm.s.Y[nb * 16 + l16][quad * 8];
            acc[nb] = __builtin_amdgcn_mfma_f32_16x16x32_f16(af, bf, acc[nb], 0, 0, 0);
        }
    }
    float bias[4];
    #pragma unroll
    for (int rg = 0; rg < 4; ++rg) bias[rg] = b_out[c0 + w * 16 + quad * 4 + rg];
    __syncthreads();
    #pragma unroll
    for (int nb = 0; nb < 4; ++nb)
        #pragma unroll
        for (int rg = 0; rg < 4; ++rg)
            sm.Os[w * 16 + quad * 4 + rg][nb * 16 + l16] = acc[nb][rg] + bias[rg];
    __syncthreads();
    const float* xp = x + ((size_t)b * C_ + c0) * N_ + n0;
    float* op = out + ((size_t)b * C_ + c0) * N_ + n0;
    #pragma unroll
    for (int r = 0; r < 4; ++r) {
        int idx = r * 256 + t;
        int c = idx >> 4, ng = (idx & 15) * 4;
        f32x4 v  = *(const f32x4*)&sm.Os[c][ng];
        f32x4 xv = *(const f32x4*)(xp + (size_t)c * N_ + ng);
        f32x4 o  = { v[0] + xv[0], v[1] + xv[1], v[2] + xv[2], v[3] + xv[3] };
        *(f32x4*)(op + (size_t)c * N_ + ng) = o;
    }
}

// ---------------------------------------------------------------------------
// Workspace map (f16 element offsets; total ~35.1 MB):
//   xT 0 (2,097,152) | wh 2,097,152 (196,608) | w_outT 2,293,760 (65,536)
//   qT 2,359,296 | kT 4,456,448 | vB 6,553,600 (2,097,152 each)
//   opart 8,650,752 (8,388,608 = 4 splits x 8 bh x 4096 x 64)
//   mpart f32 @ +17,039,360 (131,072) ; lpart follows
// ---------------------------------------------------------------------------
extern "C" void kernel_launch(void* const* d_in, const int* in_sizes, int n_in,
                              void* d_out, int out_size, void* d_ws, size_t ws_size,
                              hipStream_t stream) {
    const float* x       = (const float*)d_in[0];
    const float* w_embed = (const float*)d_in[1];
    const float* b_embed = (const float*)d_in[2];
    const float* w_out   = (const float*)d_in[3];
    const float* b_out   = (const float*)d_in[4];
    float* out = (float*)d_out;

    _Float16* base   = (_Float16*)d_ws;
    _Float16* xT     = base;
    _Float16* wh     = base + 2097152;
    _Float16* w_outT = base + 2293760;
    _Float16* qT     = base + 2359296;
    _Float16* kT     = base + 4456448;
    _Float16* vB     = base + 6553600;
    _Float16* opart  = base + 8650752;
    float*    mpart  = (float*)(base + 17039360);
    float*    lpart  = mpart + 131072;

    prep_kernel<<<dim3(624, 1, 1), 256, 0, stream>>>(x, w_embed, w_out, xT, wh, w_outT);
    qkv_gemm   <<<dim3(64, 12, 2), 256, 0, stream>>>(xT, wh, b_embed, qT, kT, vB);
    attn_kernel<<<dim3(32, 4, 8),  256, 0, stream>>>(qT, kT, vB, opart, mpart, lpart);
    proj_gemm  <<<dim3(64, 4, 2),  256, 0, stream>>>(opart, mpart, lpart, w_outT, b_out, x, out);
}